// Round 2
// baseline (5166.776 us; speedup 1.0000x reference)
//
#include <hip/hip_runtime.h>
#include <hip/hip_bf16.h>
#include <math.h>

#define BB 4
#define NN 2048
#define KK 32
#define GG 2
constexpr int BNr = BB * NN;       // 8192 point-rows per group
constexpr int SGr = BB * NN * KK;  // 262144 sample rows per group
constexpr int SR  = GG * SGr;      // 524288 total sample rows

typedef __hip_bfloat16 bf16;
__device__ __forceinline__ float b2f(bf16 v) { return __bfloat162float(v); }
__device__ __forceinline__ bf16  f2b(float v) { return __float2bfloat16(v); }

// ---------------------------------------------------------------- kNN ------
__global__ __launch_bounds__(256) void knn_kernel(const float* __restrict__ src,
                                                  const float* __restrict__ tgt,
                                                  int* __restrict__ idx_out) {
    __shared__ float pts[3 * NN];
    __shared__ float xxs[NN];
    __shared__ float d2s[NN];
    __shared__ float rval[256];
    __shared__ int   ridx[256];
    int blk = blockIdx.x;                    // g*B*N + b*N + n
    int g = blk / (BB * NN);
    int rem = blk - g * (BB * NN);
    int b = rem / NN;
    int n = rem - b * NN;
    const float* x = (g == 0 ? src : tgt) + (size_t)b * 3 * NN;
    int t = threadIdx.x;
    for (int i = t; i < 3 * NN; i += 256) pts[i] = x[i];
    __syncthreads();
    for (int m = t; m < NN; m += 256) {
        float p0 = pts[m], p1 = pts[NN + m], p2 = pts[2 * NN + m];
        xxs[m] = p0 * p0 + p1 * p1 + p2 * p2;
    }
    __syncthreads();
    float q0 = pts[n], q1 = pts[NN + n], q2 = pts[2 * NN + n];
    float xxn = xxs[n];
    for (int m = t; m < NN; m += 256) {
        float dot = q0 * pts[m] + q1 * pts[NN + m] + q2 * pts[2 * NN + m];
        d2s[m] = (xxn - 2.0f * dot) + xxs[m];
    }
    __syncthreads();
    int* outp = idx_out + (size_t)blk * KK;
    for (int k = 0; k < KK; ++k) {
        float best = INFINITY; int bi = 0x7fffffff;
        for (int m = t; m < NN; m += 256) {
            float v = d2s[m];
            if (v < best) { best = v; bi = m; }
        }
        rval[t] = best; ridx[t] = bi;
        __syncthreads();
        for (int s = 128; s > 0; s >>= 1) {
            if (t < s) {
                float ov = rval[t + s]; int oi = ridx[t + s];
                if (ov < rval[t] || (ov == rval[t] && oi < ridx[t])) {
                    rval[t] = ov; ridx[t] = oi;
                }
            }
            __syncthreads();
        }
        if (t == 0) { outp[k] = ridx[0]; d2s[ridx[0]] = INFINITY; }
        __syncthreads();
    }
}

// ---------------------------------------------------------------- zero ----
__global__ void zero_kernel(float* __restrict__ p, int n) {
    int i = blockIdx.x * 256 + threadIdx.x;
    if (i < n) p[i] = 0.f;
}

// ------------------------------------------------------------ finalize ----
__global__ void finalize_bn_kernel(const float* __restrict__ sums, int C,
                                   const float* __restrict__ gamma,
                                   const float* __restrict__ beta,
                                   float cnt, float* __restrict__ params) {
    int i = blockIdx.x * blockDim.x + threadIdx.x;
    if (i >= GG * C) return;
    int g = i / C, c = i - g * C;
    float s  = sums[(g * 512 + c) * 2 + 0];
    float sq = sums[(g * 512 + c) * 2 + 1];
    float mean = s / cnt;
    float var = sq / cnt - mean * mean;
    if (var < 0.f) var = 0.f;
    float sc = gamma[c] * rsqrtf(var + 1e-5f);
    params[(g * 512 + c) * 2 + 0] = sc;
    params[(g * 512 + c) * 2 + 1] = beta[c] - mean * sc;
}

// ----------------------------------------------------------- l1 stats -----
// 64 rows/block; compute h1pre = feat @ w1^T on the fly, per-channel stats.
__global__ __launch_bounds__(256) void l1stats_kernel(const float* __restrict__ src,
                                                      const float* __restrict__ tgt,
                                                      const float* __restrict__ w1,
                                                      const int* __restrict__ idx,
                                                      float* __restrict__ sums) {
    __shared__ float feat[64][8];
    __shared__ float w1s[64][8];
    __shared__ float epi[16][128];
    int t = threadIdx.x;
    int row0 = blockIdx.x * 64;
    int g = row0 / SGr;
    for (int i = t; i < 384; i += 256) w1s[i / 6][i % 6] = w1[i];
    if (t < 64) {
        int rr = row0 + t;
        int nrow = rr >> 5;
        int n = nrow & (NN - 1);
        int gb = nrow >> 11;
        int b = gb & 3, gg = gb >> 2;
        const float* x = (gg ? tgt : src) + (size_t)b * 3 * NN;
        int j = idx[rr];
        feat[t][0] = x[j]; feat[t][1] = x[NN + j]; feat[t][2] = x[2 * NN + j];
        feat[t][3] = x[n]; feat[t][4] = x[NN + n]; feat[t][5] = x[2 * NN + n];
    }
    __syncthreads();
    int ty = t >> 4, tx = t & 15;
    float acc[4][4] = {};
#pragma unroll
    for (int c = 0; c < 6; ++c) {
        float av[4], bv[4];
#pragma unroll
        for (int i = 0; i < 4; ++i) av[i] = feat[ty * 4 + i][c];
#pragma unroll
        for (int j = 0; j < 4; ++j) bv[j] = w1s[tx * 4 + j][c];
#pragma unroll
        for (int i = 0; i < 4; ++i)
#pragma unroll
            for (int j = 0; j < 4; ++j) acc[i][j] = fmaf(av[i], bv[j], acc[i][j]);
    }
#pragma unroll
    for (int j = 0; j < 4; ++j) {
        float s = acc[0][j] + acc[1][j] + acc[2][j] + acc[3][j];
        float q = acc[0][j] * acc[0][j] + acc[1][j] * acc[1][j] +
                  acc[2][j] * acc[2][j] + acc[3][j] * acc[3][j];
        epi[ty][tx * 4 + j] = s;
        epi[ty][64 + tx * 4 + j] = q;
    }
    __syncthreads();
    if (t < 64) {
        float s = 0.f, q = 0.f;
        for (int r = 0; r < 16; ++r) { s += epi[r][t]; q += epi[r][64 + t]; }
        atomicAdd(&sums[(g * 512 + t) * 2 + 0], s);
        atomicAdd(&sums[(g * 512 + t) * 2 + 1], q);
    }
}

// ----------------------------------------------- layers 1+2 chain ---------
// Recompute gather + h1(bn1,relu) -> F1, then h2 = F1 @ w2^T.
// APPLY=0: accumulate h2pre stats.  APPLY=1: bn2+relu -> H2 (bf16),
// plus x1 (from F1) and x2 maxes -> cat.
template <int APPLY>
__global__ __launch_bounds__(256) void l2chain_kernel(
    const float* __restrict__ src, const float* __restrict__ tgt,
    const float* __restrict__ w1, const float* __restrict__ w2,
    const int* __restrict__ idx, const float* __restrict__ p1,
    const float* __restrict__ p2, bf16* __restrict__ H2,
    bf16* __restrict__ cat, float* __restrict__ sums) {
    __shared__ float feat[64][8];
    __shared__ float w1s[64][8];
    __shared__ float F1[64][68];
    __shared__ float w2s[64][68];
    __shared__ float epi[16][128];
    int t = threadIdx.x;
    int row0 = blockIdx.x * 64;
    int g = row0 / SGr;
    for (int i = t; i < 384; i += 256) w1s[i / 6][i % 6] = w1[i];
    for (int i = t; i < 4096; i += 256) w2s[i >> 6][i & 63] = w2[i];
    if (t < 64) {
        int rr = row0 + t;
        int nrow = rr >> 5;
        int n = nrow & (NN - 1);
        int gb = nrow >> 11;
        int b = gb & 3, gg = gb >> 2;
        const float* x = (gg ? tgt : src) + (size_t)b * 3 * NN;
        int j = idx[rr];
        feat[t][0] = x[j]; feat[t][1] = x[NN + j]; feat[t][2] = x[2 * NN + j];
        feat[t][3] = x[n]; feat[t][4] = x[NN + n]; feat[t][5] = x[2 * NN + n];
    }
    __syncthreads();
    int ty = t >> 4, tx = t & 15;
    float acc[4][4] = {};
#pragma unroll
    for (int c = 0; c < 6; ++c) {
        float av[4], bv[4];
#pragma unroll
        for (int i = 0; i < 4; ++i) av[i] = feat[ty * 4 + i][c];
#pragma unroll
        for (int j = 0; j < 4; ++j) bv[j] = w1s[tx * 4 + j][c];
#pragma unroll
        for (int i = 0; i < 4; ++i)
#pragma unroll
            for (int j = 0; j < 4; ++j) acc[i][j] = fmaf(av[i], bv[j], acc[i][j]);
    }
#pragma unroll
    for (int j = 0; j < 4; ++j) {
        int o = tx * 4 + j;
        float sc = p1[(g * 512 + o) * 2], sh = p1[(g * 512 + o) * 2 + 1];
#pragma unroll
        for (int i = 0; i < 4; ++i) {
            float v = fmaf(acc[i][j], sc, sh);
            v = v > 0.f ? v : 0.f;
            acc[i][j] = v;
            F1[ty * 4 + i][tx * 4 + j] = v;
        }
    }
    __syncthreads();
    if (APPLY) {
        // x1 max (rows ty*4..+3 stay within one point: ty<8 -> point0)
#pragma unroll
        for (int j = 0; j < 4; ++j) {
            float m = fmaxf(fmaxf(acc[0][j], acc[1][j]), fmaxf(acc[2][j], acc[3][j]));
            epi[ty][tx * 4 + j] = m;
        }
        __syncthreads();
        if (t < 128) {
            int pt = t >> 6, o = t & 63;
            float m = 0.f;
            for (int r = pt * 8; r < pt * 8 + 8; ++r) m = fmaxf(m, epi[r][o]);
            cat[((size_t)(row0 >> 5) + pt) * 512 + o] = f2b(m);
        }
        __syncthreads();
    }
    float a2[4][4] = {};
#pragma unroll 8
    for (int kk = 0; kk < 64; ++kk) {
        float av[4], bv[4];
#pragma unroll
        for (int i = 0; i < 4; ++i) av[i] = F1[ty * 4 + i][kk];
#pragma unroll
        for (int j = 0; j < 4; ++j) bv[j] = w2s[tx * 4 + j][kk];
#pragma unroll
        for (int i = 0; i < 4; ++i)
#pragma unroll
            for (int j = 0; j < 4; ++j) a2[i][j] = fmaf(av[i], bv[j], a2[i][j]);
    }
    if (!APPLY) {
#pragma unroll
        for (int j = 0; j < 4; ++j) {
            float s = a2[0][j] + a2[1][j] + a2[2][j] + a2[3][j];
            float q = a2[0][j] * a2[0][j] + a2[1][j] * a2[1][j] +
                      a2[2][j] * a2[2][j] + a2[3][j] * a2[3][j];
            epi[ty][tx * 4 + j] = s;
            epi[ty][64 + tx * 4 + j] = q;
        }
        __syncthreads();
        if (t < 64) {
            float s = 0.f, q = 0.f;
            for (int r = 0; r < 16; ++r) { s += epi[r][t]; q += epi[r][64 + t]; }
            atomicAdd(&sums[(g * 512 + t) * 2 + 0], s);
            atomicAdd(&sums[(g * 512 + t) * 2 + 1], q);
        }
    } else {
#pragma unroll
        for (int j = 0; j < 4; ++j) {
            int o = tx * 4 + j;
            float sc = p2[(g * 512 + o) * 2], sh = p2[(g * 512 + o) * 2 + 1];
            float m = 0.f;
#pragma unroll
            for (int i = 0; i < 4; ++i) {
                float v = fmaf(a2[i][j], sc, sh);
                v = v > 0.f ? v : 0.f;
                H2[(size_t)(row0 + ty * 4 + i) * 64 + o] = f2b(v);
                m = fmaxf(m, v);
            }
            epi[ty][o] = m;
        }
        __syncthreads();
        if (t < 128) {
            int pt = t >> 6, o = t & 63;
            float m = 0.f;
            for (int r = pt * 8; r < pt * 8 + 8; ++r) m = fmaxf(m, epi[r][o]);
            cat[((size_t)(row0 >> 5) + pt) * 512 + 64 + o] = f2b(m);
        }
    }
}

// ----------------------------------------------- layers 3+4 chain ---------
// Read H2 (bf16), h3 = A2 @ w3^T (bn3+relu -> F3 in LDS, never stored),
// h4 = F3 @ w4^T in 8 chunks of 32 out-channels.
// APPLY=0: h4pre stats.  APPLY=1: bn4+relu+max -> cat x4, plus x3 from F3.
template <int APPLY>
__global__ __launch_bounds__(256) void chain34_kernel(
    const bf16* __restrict__ H2, const float* __restrict__ w3,
    const float* __restrict__ w4, const float* __restrict__ p3,
    const float* __restrict__ p4, bf16* __restrict__ cat,
    float* __restrict__ sums) {
    __shared__ char smem[59392];
    float* A2  = (float*)smem;             // [64][68]   (stage A)
    float* w3s = (float*)(smem + 17408);   // [128][68]  (stage A)
    float* F3  = (float*)smem;             // [64][132]  (stage B, overlaps A)
    float* w4c = (float*)(smem + 33792);   // [32][132]
    float* epi = (float*)(smem + 50688);   // [32][64]
    int t = threadIdx.x;
    int row0 = blockIdx.x * 64;
    int g = row0 / SGr;
    for (int i = t; i < 4096; i += 256) {
        int r = i >> 6, k = i & 63;
        A2[r * 68 + k] = b2f(H2[(size_t)(row0 + r) * 64 + k]);
    }
    for (int i = t; i < 8192; i += 256) {
        int o = i >> 6, k = i & 63;
        w3s[o * 68 + k] = w3[i];
    }
    __syncthreads();
    int ty = t >> 4, tx = t & 15;
    float acc3[4][8] = {};
    for (int kk = 0; kk < 64; ++kk) {
        float av[4], bv[8];
#pragma unroll
        for (int i = 0; i < 4; ++i) av[i] = A2[(ty * 4 + i) * 68 + kk];
#pragma unroll
        for (int j = 0; j < 8; ++j) bv[j] = w3s[(tx * 8 + j) * 68 + kk];
#pragma unroll
        for (int i = 0; i < 4; ++i)
#pragma unroll
            for (int j = 0; j < 8; ++j) acc3[i][j] = fmaf(av[i], bv[j], acc3[i][j]);
    }
    __syncthreads();   // all A2/w3s reads complete before F3 overwrites them
#pragma unroll
    for (int j = 0; j < 8; ++j) {
        int o = tx * 8 + j;
        float sc = p3[(g * 512 + o) * 2], sh = p3[(g * 512 + o) * 2 + 1];
#pragma unroll
        for (int i = 0; i < 4; ++i) {
            float v = fmaf(acc3[i][j], sc, sh);
            v = v > 0.f ? v : 0.f;
            F3[(ty * 4 + i) * 132 + o] = v;
        }
    }
    __syncthreads();
    int tyy = t >> 3, txx = t & 7;
    for (int co = 0; co < 8; ++co) {
        for (int i = t; i < 4096; i += 256) {
            int o = i >> 7, k = i & 127;
            w4c[o * 132 + k] = w4[(size_t)(co * 32 + o) * 128 + k];
        }
        __syncthreads();
        float a4[2][4] = {};
        for (int kk = 0; kk < 128; ++kk) {
            float av[2], bv[4];
            av[0] = F3[(tyy * 2) * 132 + kk];
            av[1] = F3[(tyy * 2 + 1) * 132 + kk];
#pragma unroll
            for (int j = 0; j < 4; ++j) bv[j] = w4c[(txx * 4 + j) * 132 + kk];
#pragma unroll
            for (int i = 0; i < 2; ++i)
#pragma unroll
                for (int j = 0; j < 4; ++j) a4[i][j] = fmaf(av[i], bv[j], a4[i][j]);
        }
        if (!APPLY) {
#pragma unroll
            for (int j = 0; j < 4; ++j) {
                int c = txx * 4 + j;
                float s = a4[0][j] + a4[1][j];
                float q = a4[0][j] * a4[0][j] + a4[1][j] * a4[1][j];
                epi[tyy * 64 + c] = s;
                epi[tyy * 64 + 32 + c] = q;
            }
            __syncthreads();
            if (t < 32) {
                float s = 0.f, q = 0.f;
                for (int r = 0; r < 32; ++r) { s += epi[r * 64 + t]; q += epi[r * 64 + 32 + t]; }
                atomicAdd(&sums[(g * 512 + co * 32 + t) * 2 + 0], s);
                atomicAdd(&sums[(g * 512 + co * 32 + t) * 2 + 1], q);
            }
            __syncthreads();
        } else {
#pragma unroll
            for (int j = 0; j < 4; ++j) {
                int c = txx * 4 + j;
                float sc = p4[(g * 512 + co * 32 + c) * 2];
                float sh = p4[(g * 512 + co * 32 + c) * 2 + 1];
                float v0 = fmaf(a4[0][j], sc, sh); v0 = v0 > 0.f ? v0 : 0.f;
                float v1 = fmaf(a4[1][j], sc, sh); v1 = v1 > 0.f ? v1 : 0.f;
                epi[tyy * 64 + c] = fmaxf(v0, v1);   // rows 2tyy,2tyy+1 same point
            }
            __syncthreads();
            if (t < 64) {
                int pt = t >> 5, c = t & 31;
                float m = 0.f;
                for (int r = pt * 16; r < pt * 16 + 16; ++r) m = fmaxf(m, epi[r * 64 + c]);
                cat[((size_t)(row0 >> 5) + pt) * 512 + 256 + co * 32 + c] = f2b(m);
            }
            __syncthreads();
        }
    }
    if (APPLY) {
        int pt = t >> 7, c = t & 127;
        float m = 0.f;
        for (int r = pt * 32; r < pt * 32 + 32; ++r) m = fmaxf(m, F3[r * 132 + c]);
        cat[((size_t)(row0 >> 5) + pt) * 512 + 128 + c] = f2b(m);
    }
}

// ------------------------------------------------------ generic GEMM ------
// out[row,o] = sum_c A[row,c] * W[o,c].  A may be bf16 (ABF16).
// MODE 0: store. MODE 1: per-channel sum/sumsq only. MODE 2: BN+ReLU+store.
template <int MODE, int ABF16>
__global__ __launch_bounds__(256) void gemm_kernel(
    const void* __restrict__ Av, const float* __restrict__ W, float* __restrict__ Out,
    int Cin, int Cout, long long sA, long long sW, long long sO,
    int rowsPerGroup, const float* __restrict__ params, float* __restrict__ sums) {
    __shared__ float As[64][68];
    __shared__ float Ws[64][68];   // [kk][o]
    __shared__ float epi[16 * 128];
    int t = threadIdx.x;
    int bz = blockIdx.z;
    const float* Wp = W + (size_t)bz * sW;
    int row0 = blockIdx.x * 64, o0 = blockIdx.y * 64;
    int ty = t >> 4, tx = t & 15;
    float acc[4][4] = {};
    for (int k0 = 0; k0 < Cin; k0 += 64) {
#pragma unroll
        for (int i = 0; i < 16; ++i) {
            int e = t + i * 256;
            int r = e >> 6, kk = e & 63;
            size_t ai = (size_t)bz * sA + (size_t)(row0 + r) * Cin + (k0 + kk);
            As[r][kk] = ABF16 ? b2f(((const bf16*)Av)[ai]) : ((const float*)Av)[ai];
            Ws[kk][r] = Wp[(size_t)(o0 + r) * Cin + (k0 + kk)];
        }
        __syncthreads();
#pragma unroll 16
        for (int kk = 0; kk < 64; ++kk) {
            float av[4], bv[4];
#pragma unroll
            for (int i = 0; i < 4; ++i) av[i] = As[ty * 4 + i][kk];
#pragma unroll
            for (int j = 0; j < 4; ++j) bv[j] = Ws[kk][tx * 4 + j];
#pragma unroll
            for (int i = 0; i < 4; ++i)
#pragma unroll
                for (int j = 0; j < 4; ++j)
                    acc[i][j] = fmaf(av[i], bv[j], acc[i][j]);
        }
        __syncthreads();
    }

    if (MODE == 0) {
        float* Outp = Out + (size_t)bz * sO;
#pragma unroll
        for (int i = 0; i < 4; ++i) {
            float4 v = make_float4(acc[i][0], acc[i][1], acc[i][2], acc[i][3]);
            *(float4*)&Outp[(size_t)(row0 + ty * 4 + i) * Cout + o0 + tx * 4] = v;
        }
    } else if (MODE == 1) {
        int g = row0 / rowsPerGroup;
#pragma unroll
        for (int j = 0; j < 4; ++j) {
            float s = acc[0][j] + acc[1][j] + acc[2][j] + acc[3][j];
            float q = acc[0][j] * acc[0][j] + acc[1][j] * acc[1][j] +
                      acc[2][j] * acc[2][j] + acc[3][j] * acc[3][j];
            epi[ty * 128 + (tx * 4 + j) * 2 + 0] = s;
            epi[ty * 128 + (tx * 4 + j) * 2 + 1] = q;
        }
        __syncthreads();
        if (t < 64) {
            float s = 0.f, q = 0.f;
            for (int r = 0; r < 16; ++r) {
                s += epi[r * 128 + t * 2];
                q += epi[r * 128 + t * 2 + 1];
            }
            atomicAdd(&sums[(g * 512 + o0 + t) * 2 + 0], s);
            atomicAdd(&sums[(g * 512 + o0 + t) * 2 + 1], q);
        }
    } else {  // MODE 2
        int g = row0 / rowsPerGroup;
        float* Outp = Out + (size_t)bz * sO;
#pragma unroll
        for (int j = 0; j < 4; ++j) {
            int col = o0 + tx * 4 + j;
            float sc = params[(g * 512 + col) * 2], sh = params[(g * 512 + col) * 2 + 1];
#pragma unroll
            for (int i = 0; i < 4; ++i) {
                float v = fmaf(acc[i][j], sc, sh);
                acc[i][j] = v > 0.f ? v : 0.f;
            }
        }
#pragma unroll
        for (int i = 0; i < 4; ++i) {
            float4 v = make_float4(acc[i][0], acc[i][1], acc[i][2], acc[i][3]);
            *(float4*)&Outp[(size_t)(row0 + ty * 4 + i) * Cout + o0 + tx * 4] = v;
        }
    }
}

// ------------------------------------------------------------ norms -------
__global__ __launch_bounds__(256) void norms_kernel(const float* __restrict__ emb,
                                                    float* __restrict__ nrm) {
    __shared__ float red[256];
    int row = blockIdx.x; int t = threadIdx.x;
    float s = 0.f;
    for (int c = t; c < 512; c += 256) { float v = emb[(size_t)row * 512 + c]; s += v * v; }
    red[t] = s; __syncthreads();
    for (int st = 128; st > 0; st >>= 1) { if (t < st) red[t] += red[t + st]; __syncthreads(); }
    if (t == 0) nrm[row] = red[0];
}

// -------------------------------- distance + softmax + weighted sum -------
__global__ __launch_bounds__(256) void corr_kernel(const float* __restrict__ inner,
                                                   const float* __restrict__ nrm,
                                                   const float* __restrict__ tgt,
                                                   float* __restrict__ out) {
    __shared__ float red[256];
    int blk = blockIdx.x;                 // b*N + n
    int b = blk >> 11, n = blk & (NN - 1);
    int t = threadIdx.x;
    const float* inr = inner + ((size_t)b * NN + n) * NN;
    float xx = nrm[b * NN + n];
    float dloc[8];
    float vmax = -INFINITY;
#pragma unroll
    for (int i = 0; i < 8; ++i) {
        int m = t + i * 256;
        float pd = (xx - 2.f * inr[m]) + nrm[BNr + b * NN + m];
        float d = pd > 0.f ? sqrtf(pd) : 0.f;
        dloc[i] = d;
        vmax = fmaxf(vmax, -d);
    }
    red[t] = vmax; __syncthreads();
    for (int s = 128; s > 0; s >>= 1) { if (t < s) red[t] = fmaxf(red[t], red[t + s]); __syncthreads(); }
    vmax = red[0]; __syncthreads();
    const float* tp = tgt + (size_t)b * 3 * NN;
    float se = 0.f, s0 = 0.f, s1 = 0.f, s2 = 0.f;
#pragma unroll
    for (int i = 0; i < 8; ++i) {
        int m = t + i * 256;
        float p = expf(-dloc[i] - vmax);
        se += p;
        s0 += p * tp[m]; s1 += p * tp[NN + m]; s2 += p * tp[2 * NN + m];
    }
    red[t] = se; __syncthreads();
    for (int s = 128; s > 0; s >>= 1) { if (t < s) red[t] += red[t + s]; __syncthreads(); }
    float tot = red[0]; __syncthreads();
    red[t] = s0; __syncthreads();
    for (int s = 128; s > 0; s >>= 1) { if (t < s) red[t] += red[t + s]; __syncthreads(); }
    float o0v = red[0]; __syncthreads();
    red[t] = s1; __syncthreads();
    for (int s = 128; s > 0; s >>= 1) { if (t < s) red[t] += red[t + s]; __syncthreads(); }
    float o1v = red[0]; __syncthreads();
    red[t] = s2; __syncthreads();
    for (int s = 128; s > 0; s >>= 1) { if (t < s) red[t] += red[t + s]; __syncthreads(); }
    float o2v = red[0];
    if (t == 0) {
        out[(size_t)b * 3 * NN + n]          = o0v / tot;
        out[(size_t)b * 3 * NN + NN + n]     = o1v / tot;
        out[(size_t)b * 3 * NN + 2 * NN + n] = o2v / tot;
    }
}

// ------------------------------------------------------------- driver -----
extern "C" void kernel_launch(void* const* d_in, const int* in_sizes, int n_in,
                              void* d_out, int out_size, void* d_ws, size_t ws_size,
                              hipStream_t stream) {
    const float* src = (const float*)d_in[0];
    const float* tgt = (const float*)d_in[1];
    const float* w1  = (const float*)d_in[2];
    const float* w2  = (const float*)d_in[3];
    const float* w3  = (const float*)d_in[4];
    const float* w4  = (const float*)d_in[5];
    const float* w5  = (const float*)d_in[6];
    const float* g1  = (const float*)d_in[7];
    const float* g2  = (const float*)d_in[8];
    const float* g3  = (const float*)d_in[9];
    const float* g4  = (const float*)d_in[10];
    const float* g5  = (const float*)d_in[11];
    const float* b1  = (const float*)d_in[12];
    const float* b2  = (const float*)d_in[13];
    const float* b3  = (const float*)d_in[14];
    const float* b4  = (const float*)d_in[15];
    const float* b5  = (const float*)d_in[16];
    float* out = (float*)d_out;
    char* ws = (char*)d_ws;
    (void)in_sizes; (void)n_in;

    size_t off = 0;
    auto alloc = [&](size_t bytes) { size_t o = off; off = (off + bytes + 255) & ~(size_t)255; return o; };
    int*   idx  = (int*)(ws + alloc((size_t)SR * 4));                 // 2 MB
    bf16*  H2   = (bf16*)(ws + alloc((size_t)SR * 64 * 2));           // 67 MB (also inner f32)
    bf16*  cat  = (bf16*)(ws + alloc((size_t)GG * BNr * 512 * 2));    // 16.8 MB
    float* emb  = (float*)(ws + alloc((size_t)GG * BNr * 512 * 4));   // 33.5 MB
    float* nrm  = (float*)(ws + alloc((size_t)GG * BNr * 4));
    float* sums = (float*)(ws + alloc(2048 * 4));
    float* prm  = (float*)(ws + alloc(5 * 2048 * 4));
    float* P1 = prm, *P2 = prm + 2048, *P3 = prm + 4096, *P4 = prm + 6144, *P5 = prm + 8192;
    float* inner = (float*)H2;   // overlay: SR*64*2 bytes == B*N*N*4 bytes exactly

    if (ws_size < off) {   // distinguishable failure instead of OOB fault
        hipMemsetAsync(d_out, 0, (size_t)out_size * 4, stream);
        return;
    }

    knn_kernel<<<GG * BB * NN, 256, 0, stream>>>(src, tgt, idx);

    // layer 1: stats -> params1
    zero_kernel<<<8, 256, 0, stream>>>(sums, 2048);
    l1stats_kernel<<<SR / 64, 256, 0, stream>>>(src, tgt, w1, idx, sums);
    finalize_bn_kernel<<<1, 128, 0, stream>>>(sums, 64, g1, b1, (float)SGr, P1);

    // layer 2: stats then apply (writes H2 + x1,x2)
    zero_kernel<<<8, 256, 0, stream>>>(sums, 2048);
    l2chain_kernel<0><<<SR / 64, 256, 0, stream>>>(src, tgt, w1, w2, idx, P1, nullptr, nullptr, nullptr, sums);
    finalize_bn_kernel<<<1, 128, 0, stream>>>(sums, 64, g2, b2, (float)SGr, P2);
    l2chain_kernel<1><<<SR / 64, 256, 0, stream>>>(src, tgt, w1, w2, idx, P1, P2, H2, cat, nullptr);

    // layer 3 stats (GEMM on H2, no store)
    zero_kernel<<<8, 256, 0, stream>>>(sums, 2048);
    gemm_kernel<1, 1><<<dim3(SR / 64, 2, 1), 256, 0, stream>>>(H2, w3, nullptr, 64, 128, 0, 0, 0, SGr, nullptr, sums);
    finalize_bn_kernel<<<2, 128, 0, stream>>>(sums, 128, g3, b3, (float)SGr, P3);

    // layer 4: stats then apply (writes x3,x4)
    zero_kernel<<<8, 256, 0, stream>>>(sums, 2048);
    chain34_kernel<0><<<SR / 64, 256, 0, stream>>>(H2, w3, w4, P3, nullptr, nullptr, sums);
    finalize_bn_kernel<<<4, 128, 0, stream>>>(sums, 256, g4, b4, (float)SGr, P4);
    chain34_kernel<1><<<SR / 64, 256, 0, stream>>>(H2, w3, w4, P3, P4, cat, nullptr);

    // layer 5: stats then apply -> emb (f32)
    zero_kernel<<<8, 256, 0, stream>>>(sums, 2048);
    gemm_kernel<1, 1><<<dim3(GG * BNr / 64, 8, 1), 256, 0, stream>>>(cat, w5, nullptr, 512, 512, 0, 0, 0, BNr, nullptr, sums);
    finalize_bn_kernel<<<8, 128, 0, stream>>>(sums, 512, g5, b5, (float)BNr, P5);
    gemm_kernel<2, 1><<<dim3(GG * BNr / 64, 8, 1), 256, 0, stream>>>(cat, w5, emb, 512, 512, 0, 0, 0, BNr, P5, nullptr);

    // embedding norms
    norms_kernel<<<GG * BNr, 256, 0, stream>>>(emb, nrm);

    // inner products: per-batch emb_src x emb_tgt^T -> inner (overlaid on H2)
    gemm_kernel<0, 0><<<dim3(NN / 64, NN / 64, BB), 256, 0, stream>>>(
        emb, emb + (size_t)BNr * 512, inner, 512, 2048,
        (long long)NN * 512, (long long)NN * 512, (long long)NN * NN,
        SGr, nullptr, nullptr);

    // distance + softmax + weighted sum of tgt points
    corr_kernel<<<BB * NN, 256, 0, stream>>>(inner, nrm, tgt, out);
}

// Round 3
// 2125.964 us; speedup vs baseline: 2.4303x; 2.4303x over previous
//
#include <hip/hip_runtime.h>
#include <hip/hip_bf16.h>
#include <math.h>

#define BB 4
#define NN 2048
#define KK 32
#define GG 2
constexpr int BNr = BB * NN;       // 8192 point-rows per group
constexpr int SGr = BB * NN * KK;  // 262144 sample rows per group
constexpr int SR  = GG * SGr;      // 524288 total sample rows

typedef __hip_bfloat16 bf16;
typedef __attribute__((ext_vector_type(8))) short bf16x8;
typedef __attribute__((ext_vector_type(4))) float f32x4;
__device__ __forceinline__ float b2f(bf16 v) { return __bfloat162float(v); }
__device__ __forceinline__ bf16  f2b(float v) { return __float2bfloat16(v); }

// XOR swizzles for LDS tiles (byte-offset based; row = stride 128B / 256B)
#define SWZ128(b) ((b) ^ ((((b) >> 7) & 7) << 4))
#define SWZ256(b) ((b) ^ ((((b) >> 8) & 7) << 4))

// ---------------------------------------------------------------- kNN ------
__global__ __launch_bounds__(256) void knn_kernel(const float* __restrict__ src,
                                                  const float* __restrict__ tgt,
                                                  int* __restrict__ idx_out) {
    __shared__ float pts[3 * NN];
    __shared__ float xxs[NN];
    __shared__ float d2s[NN];
    __shared__ float rval[256];
    __shared__ int   ridx[256];
    int blk = blockIdx.x;                    // g*B*N + b*N + n
    int g = blk / (BB * NN);
    int rem = blk - g * (BB * NN);
    int b = rem / NN;
    int n = rem - b * NN;
    const float* x = (g == 0 ? src : tgt) + (size_t)b * 3 * NN;
    int t = threadIdx.x;
    for (int i = t; i < 3 * NN; i += 256) pts[i] = x[i];
    __syncthreads();
    for (int m = t; m < NN; m += 256) {
        float p0 = pts[m], p1 = pts[NN + m], p2 = pts[2 * NN + m];
        xxs[m] = p0 * p0 + p1 * p1 + p2 * p2;
    }
    __syncthreads();
    float q0 = pts[n], q1 = pts[NN + n], q2 = pts[2 * NN + n];
    float xxn = xxs[n];
    for (int m = t; m < NN; m += 256) {
        float dot = q0 * pts[m] + q1 * pts[NN + m] + q2 * pts[2 * NN + m];
        d2s[m] = (xxn - 2.0f * dot) + xxs[m];
    }
    __syncthreads();
    int* outp = idx_out + (size_t)blk * KK;
    for (int k = 0; k < KK; ++k) {
        float best = INFINITY; int bi = 0x7fffffff;
        for (int m = t; m < NN; m += 256) {
            float v = d2s[m];
            if (v < best) { best = v; bi = m; }
        }
        rval[t] = best; ridx[t] = bi;
        __syncthreads();
        for (int s = 128; s > 0; s >>= 1) {
            if (t < s) {
                float ov = rval[t + s]; int oi = ridx[t + s];
                if (ov < rval[t] || (ov == rval[t] && oi < ridx[t])) {
                    rval[t] = ov; ridx[t] = oi;
                }
            }
            __syncthreads();
        }
        if (t == 0) { outp[k] = ridx[0]; d2s[ridx[0]] = INFINITY; }
        __syncthreads();
    }
}

// ---------------------------------------------------------------- misc ----
__global__ void zero_kernel(float* __restrict__ p, int n) {
    int i = blockIdx.x * 256 + threadIdx.x;
    if (i < n) p[i] = 0.f;
}

__global__ void cvt_kernel(const float* __restrict__ a, bf16* __restrict__ o, int n) {
    int i = blockIdx.x * 256 + threadIdx.x;
    if (i < n) o[i] = f2b(a[i]);
}

__global__ void finalize_bn_kernel(const float* __restrict__ sums, int C,
                                   const float* __restrict__ gamma,
                                   const float* __restrict__ beta,
                                   float cnt, float* __restrict__ params) {
    int i = blockIdx.x * blockDim.x + threadIdx.x;
    if (i >= GG * C) return;
    int g = i / C, c = i - g * C;
    float s  = sums[(g * 512 + c) * 2 + 0];
    float sq = sums[(g * 512 + c) * 2 + 1];
    float mean = s / cnt;
    float var = sq / cnt - mean * mean;
    if (var < 0.f) var = 0.f;
    float sc = gamma[c] * rsqrtf(var + 1e-5f);
    params[(g * 512 + c) * 2 + 0] = sc;
    params[(g * 512 + c) * 2 + 1] = beta[c] - mean * sc;
}

// ----------------------------------------------------------- l1 stats -----
__global__ __launch_bounds__(256) void l1stats_kernel(const float* __restrict__ src,
                                                      const float* __restrict__ tgt,
                                                      const float* __restrict__ w1,
                                                      const int* __restrict__ idx,
                                                      float* __restrict__ sums) {
    __shared__ float feat[64][8];
    __shared__ float w1s[64][8];
    __shared__ float epi[16][128];
    int t = threadIdx.x;
    int row0 = blockIdx.x * 64;
    int g = row0 / SGr;
    for (int i = t; i < 384; i += 256) w1s[i / 6][i % 6] = w1[i];
    if (t < 64) {
        int rr = row0 + t;
        int nrow = rr >> 5;
        int n = nrow & (NN - 1);
        int gb = nrow >> 11;
        int b = gb & 3, gg = gb >> 2;
        const float* x = (gg ? tgt : src) + (size_t)b * 3 * NN;
        int j = idx[rr];
        feat[t][0] = x[j]; feat[t][1] = x[NN + j]; feat[t][2] = x[2 * NN + j];
        feat[t][3] = x[n]; feat[t][4] = x[NN + n]; feat[t][5] = x[2 * NN + n];
    }
    __syncthreads();
    int ty = t >> 4, tx = t & 15;
    float acc[4][4] = {};
#pragma unroll
    for (int c = 0; c < 6; ++c) {
        float av[4], bv[4];
#pragma unroll
        for (int i = 0; i < 4; ++i) av[i] = feat[ty * 4 + i][c];
#pragma unroll
        for (int j = 0; j < 4; ++j) bv[j] = w1s[tx * 4 + j][c];
#pragma unroll
        for (int i = 0; i < 4; ++i)
#pragma unroll
            for (int j = 0; j < 4; ++j) acc[i][j] = fmaf(av[i], bv[j], acc[i][j]);
    }
#pragma unroll
    for (int j = 0; j < 4; ++j) {
        float s = acc[0][j] + acc[1][j] + acc[2][j] + acc[3][j];
        float q = acc[0][j] * acc[0][j] + acc[1][j] * acc[1][j] +
                  acc[2][j] * acc[2][j] + acc[3][j] * acc[3][j];
        epi[ty][tx * 4 + j] = s;
        epi[ty][64 + tx * 4 + j] = q;
    }
    __syncthreads();
    if (t < 64) {
        float s = 0.f, q = 0.f;
        for (int r = 0; r < 16; ++r) { s += epi[r][t]; q += epi[r][64 + t]; }
        atomicAdd(&sums[(g * 512 + t) * 2 + 0], s);
        atomicAdd(&sums[(g * 512 + t) * 2 + 1], q);
    }
}

// ----------------------------------------------- layers 1+2 chain ---------
template <int APPLY>
__global__ __launch_bounds__(256) void l2chain_kernel(
    const float* __restrict__ src, const float* __restrict__ tgt,
    const float* __restrict__ w1, const float* __restrict__ w2,
    const int* __restrict__ idx, const float* __restrict__ p1,
    const float* __restrict__ p2, bf16* __restrict__ H2,
    bf16* __restrict__ cat, float* __restrict__ sums) {
    __shared__ float feat[64][8];
    __shared__ float w1s[64][8];
    __shared__ float F1[64][68];
    __shared__ float w2s[64][68];
    __shared__ float epi[16][128];
    int t = threadIdx.x;
    int row0 = blockIdx.x * 64;
    int g = row0 / SGr;
    for (int i = t; i < 384; i += 256) w1s[i / 6][i % 6] = w1[i];
    for (int i = t; i < 4096; i += 256) w2s[i >> 6][i & 63] = w2[i];
    if (t < 64) {
        int rr = row0 + t;
        int nrow = rr >> 5;
        int n = nrow & (NN - 1);
        int gb = nrow >> 11;
        int b = gb & 3, gg = gb >> 2;
        const float* x = (gg ? tgt : src) + (size_t)b * 3 * NN;
        int j = idx[rr];
        feat[t][0] = x[j]; feat[t][1] = x[NN + j]; feat[t][2] = x[2 * NN + j];
        feat[t][3] = x[n]; feat[t][4] = x[NN + n]; feat[t][5] = x[2 * NN + n];
    }
    __syncthreads();
    int ty = t >> 4, tx = t & 15;
    float acc[4][4] = {};
#pragma unroll
    for (int c = 0; c < 6; ++c) {
        float av[4], bv[4];
#pragma unroll
        for (int i = 0; i < 4; ++i) av[i] = feat[ty * 4 + i][c];
#pragma unroll
        for (int j = 0; j < 4; ++j) bv[j] = w1s[tx * 4 + j][c];
#pragma unroll
        for (int i = 0; i < 4; ++i)
#pragma unroll
            for (int j = 0; j < 4; ++j) acc[i][j] = fmaf(av[i], bv[j], acc[i][j]);
    }
#pragma unroll
    for (int j = 0; j < 4; ++j) {
        int o = tx * 4 + j;
        float sc = p1[(g * 512 + o) * 2], sh = p1[(g * 512 + o) * 2 + 1];
#pragma unroll
        for (int i = 0; i < 4; ++i) {
            float v = fmaf(acc[i][j], sc, sh);
            v = v > 0.f ? v : 0.f;
            acc[i][j] = v;
            F1[ty * 4 + i][tx * 4 + j] = v;
        }
    }
    __syncthreads();
    if (APPLY) {
#pragma unroll
        for (int j = 0; j < 4; ++j) {
            float m = fmaxf(fmaxf(acc[0][j], acc[1][j]), fmaxf(acc[2][j], acc[3][j]));
            epi[ty][tx * 4 + j] = m;
        }
        __syncthreads();
        if (t < 128) {
            int pt = t >> 6, o = t & 63;
            float m = 0.f;
            for (int r = pt * 8; r < pt * 8 + 8; ++r) m = fmaxf(m, epi[r][o]);
            cat[((size_t)(row0 >> 5) + pt) * 512 + o] = f2b(m);
        }
        __syncthreads();
    }
    float a2[4][4] = {};
#pragma unroll 8
    for (int kk = 0; kk < 64; ++kk) {
        float av[4], bv[4];
#pragma unroll
        for (int i = 0; i < 4; ++i) av[i] = F1[ty * 4 + i][kk];
#pragma unroll
        for (int j = 0; j < 4; ++j) bv[j] = w2s[tx * 4 + j][kk];
#pragma unroll
        for (int i = 0; i < 4; ++i)
#pragma unroll
            for (int j = 0; j < 4; ++j) a2[i][j] = fmaf(av[i], bv[j], a2[i][j]);
    }
    if (!APPLY) {
#pragma unroll
        for (int j = 0; j < 4; ++j) {
            float s = a2[0][j] + a2[1][j] + a2[2][j] + a2[3][j];
            float q = a2[0][j] * a2[0][j] + a2[1][j] * a2[1][j] +
                      a2[2][j] * a2[2][j] + a2[3][j] * a2[3][j];
            epi[ty][tx * 4 + j] = s;
            epi[ty][64 + tx * 4 + j] = q;
        }
        __syncthreads();
        if (t < 64) {
            float s = 0.f, q = 0.f;
            for (int r = 0; r < 16; ++r) { s += epi[r][t]; q += epi[r][64 + t]; }
            atomicAdd(&sums[(g * 512 + t) * 2 + 0], s);
            atomicAdd(&sums[(g * 512 + t) * 2 + 1], q);
        }
    } else {
#pragma unroll
        for (int j = 0; j < 4; ++j) {
            int o = tx * 4 + j;
            float sc = p2[(g * 512 + o) * 2], sh = p2[(g * 512 + o) * 2 + 1];
            float m = 0.f;
#pragma unroll
            for (int i = 0; i < 4; ++i) {
                float v = fmaf(a2[i][j], sc, sh);
                v = v > 0.f ? v : 0.f;
                H2[(size_t)(row0 + ty * 4 + i) * 64 + o] = f2b(v);
                m = fmaxf(m, v);
            }
            epi[ty][o] = m;
        }
        __syncthreads();
        if (t < 128) {
            int pt = t >> 6, o = t & 63;
            float m = 0.f;
            for (int r = pt * 8; r < pt * 8 + 8; ++r) m = fmaxf(m, epi[r][o]);
            cat[((size_t)(row0 >> 5) + pt) * 512 + 64 + o] = f2b(m);
        }
    }
}

// ------------------------------------------- MFMA chain: layers 3+4 -------
// 512 threads / 8 waves. Weights resident in LDS. 4 chunks of 128 rows.
// APPLY=0: h4pre per-channel sum/sumsq.  APPLY=1: bn4+relu+max -> cat x4,
// plus x3 max from F3.
template <int APPLY>
__global__ __launch_bounds__(512, 2) void chain34_mfma(
    const bf16* __restrict__ H2, const bf16* __restrict__ w3b,
    const bf16* __restrict__ w4b, const float* __restrict__ p3,
    const float* __restrict__ p4, bf16* __restrict__ cat,
    float* __restrict__ sums) {
    extern __shared__ char smem[];
    char* W3s = smem;                      // 16384  [128][64] bf16 swz128
    char* W4s = smem + 16384;              // 65536  [256][128] bf16 swz256
    char* A2s = smem + 81920;              // 16384  [128][64] bf16 swz128
    char* F3s = smem + 98304;              // 32768  [128][128] bf16 swz256
    float* P3s = (float*)(smem + 131072);  // 256 f32
    float* P4s = (float*)(smem + 132096);  // 512 f32
    float* epi = (float*)(smem + 134144);  // 4096 B: stats 512 f32 / apply 1024 int

    int tid = threadIdx.x;
    int w = tid >> 6, l = tid & 63, lg = l >> 4, lr = l & 15;
    long long rowB0 = (long long)blockIdx.x * 512;
    int g = (int)(rowB0 / SGr);

    for (int s = tid; s < 1024; s += 512)
        *(bf16x8*)(W3s + SWZ128(s * 16)) = *(const bf16x8*)(w3b + s * 8);
    for (int s = tid; s < 4096; s += 512)
        *(bf16x8*)(W4s + SWZ256(s * 16)) = *(const bf16x8*)(w4b + s * 8);
    if (tid < 256) P3s[tid] = p3[g * 1024 + tid];
    P4s[tid] = p4 ? p4[g * 1024 + tid] : 0.f;
    if (!APPLY) epi[tid] = 0.f;

    for (int chunk = 0; chunk < 4; ++chunk) {
        long long row0 = rowB0 + chunk * 128;
        // stage A2 tile
        for (int s = tid; s < 1024; s += 512)
            *(bf16x8*)(A2s + SWZ128(s * 16)) = *(const bf16x8*)(H2 + row0 * 64 + s * 8);
        if (APPLY) { ((int*)epi)[tid] = 0; ((int*)epi)[tid + 512] = 0; }
        __syncthreads();

        // layer 3: [128x64] @ w3^T[128x64] -> 128x128
        f32x4 acc3[8] = {};
#pragma unroll
        for (int ks = 0; ks < 2; ++ks) {
            bf16x8 a = *(bf16x8*)(A2s + SWZ128(((16 * w + lr) * 64 + ks * 32 + lg * 8) * 2));
#pragma unroll
            for (int j = 0; j < 8; ++j) {
                bf16x8 b = *(bf16x8*)(W3s + SWZ128(((16 * j + lr) * 64 + ks * 32 + lg * 8) * 2));
                acc3[j] = __builtin_amdgcn_mfma_f32_16x16x32_bf16(a, b, acc3[j], 0, 0, 0);
            }
        }
        // bn3+relu -> F3 (bf16)
#pragma unroll
        for (int j = 0; j < 8; ++j) {
            int c = 16 * j + lr;
            float sc = P3s[c * 2], sh = P3s[c * 2 + 1];
#pragma unroll
            for (int r = 0; r < 4; ++r) {
                float v = fmaf(acc3[j][r], sc, sh);
                v = v > 0.f ? v : 0.f;
                int rowi = 16 * w + 4 * lg + r;
                *(bf16*)(F3s + SWZ256((rowi * 128 + c) * 2)) = f2b(v);
            }
        }
        __syncthreads();

        // layer 4: F3[128x128] @ w4^T[256x128] -> 128x256
        f32x4 acc4[16] = {};
#pragma unroll
        for (int ks = 0; ks < 4; ++ks) {
            bf16x8 a = *(bf16x8*)(F3s + SWZ256(((16 * w + lr) * 128 + ks * 32 + lg * 8) * 2));
#pragma unroll
            for (int j = 0; j < 16; ++j) {
                bf16x8 b = *(bf16x8*)(W4s + SWZ256(((16 * j + lr) * 128 + ks * 32 + lg * 8) * 2));
                acc4[j] = __builtin_amdgcn_mfma_f32_16x16x32_bf16(a, b, acc4[j], 0, 0, 0);
            }
        }

        if (!APPLY) {
#pragma unroll
            for (int j = 0; j < 16; ++j) {
                int c = 16 * j + lr;
                float s = acc4[j][0] + acc4[j][1] + acc4[j][2] + acc4[j][3];
                float q = acc4[j][0] * acc4[j][0] + acc4[j][1] * acc4[j][1] +
                          acc4[j][2] * acc4[j][2] + acc4[j][3] * acc4[j][3];
                s += __shfl_xor(s, 16); s += __shfl_xor(s, 32);
                q += __shfl_xor(q, 16); q += __shfl_xor(q, 32);
                if (lg == 0) {
                    atomicAdd(&epi[c * 2], s);
                    atomicAdd(&epi[c * 2 + 1], q);
                }
            }
            // no sync needed: epi is atomic-accumulated; buffers rotate at stage sync
        } else {
#pragma unroll
            for (int j = 0; j < 16; ++j) {
                int c = 16 * j + lr;
                float sc = P4s[c * 2], sh = P4s[c * 2 + 1];
                float m = 0.f;
#pragma unroll
                for (int r = 0; r < 4; ++r) {
                    float v = fmaf(acc4[j][r], sc, sh);
                    v = v > 0.f ? v : 0.f;
                    m = fmaxf(m, v);
                }
                m = fmaxf(m, __shfl_xor(m, 16));
                m = fmaxf(m, __shfl_xor(m, 32));
                if (lg == 0)
                    atomicMax((int*)epi + (w >> 1) * 256 + c, __float_as_int(m));
            }
            __syncthreads();
            long long pt0 = row0 >> 5;   // 4 points per chunk
            for (int e = tid; e < 1024; e += 512) {
                int p = e >> 8, c = e & 255;
                cat[(pt0 + p) * 512 + 256 + c] = f2b(__int_as_float(((int*)epi)[p * 256 + c]));
            }
            {   // x3 from F3 (post-relu bf16)
                int p = tid >> 7, c = tid & 127;
                float m = 0.f;
                for (int r = 0; r < 32; ++r)
                    m = fmaxf(m, b2f(*(bf16*)(F3s + SWZ256(((p * 32 + r) * 128 + c) * 2))));
                cat[(pt0 + p) * 512 + 128 + c] = f2b(m);
            }
            __syncthreads();
        }
    }
    if (!APPLY) {
        __syncthreads();
        atomicAdd(&sums[g * 1024 + tid], epi[tid]);
    }
}

// ----------------------------------------------------- generic MFMA GEMM --
// A [rows x Cin] bf16, W [O x Cin] bf16, BM=128 BN=64 BK=64, 256 thr / 4 waves.
// MODE 0: store f32 to OutF. MODE 1: per-channel sum/sumsq. MODE 2: bn+relu
// -> OutB bf16.
template <int MODE, int CH>
__global__ __launch_bounds__(256, 4) void mfma_gemm(
    const bf16* __restrict__ A, const bf16* __restrict__ Wt,
    float* __restrict__ OutF, bf16* __restrict__ OutB,
    int Cin, int ldOut, long long sA, long long sW, long long sO,
    int rowsPerGroup, const float* __restrict__ params, float* __restrict__ sums) {
    __shared__ char As[16384];   // [128][64] bf16 swz128
    __shared__ char Bs[8192];    // [64][64] bf16 swz128
    __shared__ float epi[128];
    int tid = threadIdx.x;
    int w = tid >> 6, l = tid & 63, lg = l >> 4, lr = l & 15;
    int bz = blockIdx.z;
    const bf16* Ap = A + (long long)bz * sA;
    const bf16* Wp = Wt + (long long)bz * sW;
    int o0 = blockIdx.y * 64;
    long long rowB0 = (long long)blockIdx.x * (128 * CH);
    int g = (int)(rowB0 / rowsPerGroup);
    if (MODE == 1 && tid < 128) epi[tid] = 0.f;
    int wr = (w >> 1) * 64, wc = (w & 1) * 32;

    for (int ch = 0; ch < CH; ++ch) {
        long long row0 = rowB0 + (long long)ch * 128;
        f32x4 acc[4][2] = {};
        for (int k0 = 0; k0 < Cin; k0 += 64) {
            __syncthreads();
            for (int s = tid; s < 1024; s += 256)
                *(bf16x8*)(As + SWZ128(s * 16)) =
                    *(const bf16x8*)(Ap + (row0 + (s >> 3)) * Cin + k0 + (s & 7) * 8);
            for (int s = tid; s < 512; s += 256)
                *(bf16x8*)(Bs + SWZ128(s * 16)) =
                    *(const bf16x8*)(Wp + (long long)(o0 + (s >> 3)) * Cin + k0 + (s & 7) * 8);
            __syncthreads();
#pragma unroll
            for (int ks = 0; ks < 2; ++ks) {
                bf16x8 b0 = *(bf16x8*)(Bs + SWZ128(((wc + lr) * 64 + ks * 32 + lg * 8) * 2));
                bf16x8 b1 = *(bf16x8*)(Bs + SWZ128(((wc + 16 + lr) * 64 + ks * 32 + lg * 8) * 2));
#pragma unroll
                for (int i = 0; i < 4; ++i) {
                    bf16x8 a = *(bf16x8*)(As + SWZ128(((wr + 16 * i + lr) * 64 + ks * 32 + lg * 8) * 2));
                    acc[i][0] = __builtin_amdgcn_mfma_f32_16x16x32_bf16(a, b0, acc[i][0], 0, 0, 0);
                    acc[i][1] = __builtin_amdgcn_mfma_f32_16x16x32_bf16(a, b1, acc[i][1], 0, 0, 0);
                }
            }
        }
        if (MODE == 1) {
#pragma unroll
            for (int j = 0; j < 2; ++j) {
                int c = wc + 16 * j + lr;
                float s = 0.f, q = 0.f;
#pragma unroll
                for (int i = 0; i < 4; ++i)
#pragma unroll
                    for (int r = 0; r < 4; ++r) {
                        float v = acc[i][j][r];
                        s += v; q += v * v;
                    }
                s += __shfl_xor(s, 16); s += __shfl_xor(s, 32);
                q += __shfl_xor(q, 16); q += __shfl_xor(q, 32);
                if (lg == 0) {
                    atomicAdd(&epi[c * 2], s);
                    atomicAdd(&epi[c * 2 + 1], q);
                }
            }
        } else if (MODE == 2) {
#pragma unroll
            for (int j = 0; j < 2; ++j) {
                int gc = o0 + wc + 16 * j + lr;
                float sc = params[(g * 512 + gc) * 2], sh = params[(g * 512 + gc) * 2 + 1];
#pragma unroll
                for (int i = 0; i < 4; ++i)
#pragma unroll
                    for (int r = 0; r < 4; ++r) {
                        long long gr = row0 + wr + 16 * i + 4 * lg + r;
                        float v = fmaf(acc[i][j][r], sc, sh);
                        v = v > 0.f ? v : 0.f;
                        OutB[gr * ldOut + gc] = f2b(v);
                    }
            }
        } else {
            float* Op = OutF + (long long)bz * sO;
#pragma unroll
            for (int j = 0; j < 2; ++j) {
                int gc = o0 + wc + 16 * j + lr;
#pragma unroll
                for (int i = 0; i < 4; ++i)
#pragma unroll
                    for (int r = 0; r < 4; ++r) {
                        long long gr = row0 + wr + 16 * i + 4 * lg + r;
                        Op[gr * ldOut + gc] = acc[i][j][r];
                    }
            }
        }
    }
    if (MODE == 1) {
        __syncthreads();
        if (tid < 128) atomicAdd(&sums[g * 1024 + o0 * 2 + tid], epi[tid]);
    }
}

// ------------------------------------------------------------ norms -------
__global__ __launch_bounds__(256) void norms_b_kernel(const bf16* __restrict__ emb,
                                                      float* __restrict__ nrm) {
    __shared__ float red[256];
    int row = blockIdx.x; int t = threadIdx.x;
    float s = 0.f;
    for (int c = t; c < 512; c += 256) { float v = b2f(emb[(size_t)row * 512 + c]); s += v * v; }
    red[t] = s; __syncthreads();
    for (int st = 128; st > 0; st >>= 1) { if (t < st) red[t] += red[t + st]; __syncthreads(); }
    if (t == 0) nrm[row] = red[0];
}

// -------------------------------- distance + softmax + weighted sum -------
__global__ __launch_bounds__(256) void corr_kernel(const float* __restrict__ inner,
                                                   const float* __restrict__ nrm,
                                                   const float* __restrict__ tgt,
                                                   float* __restrict__ out) {
    __shared__ float red[256];
    int blk = blockIdx.x;                 // b*N + n
    int b = blk >> 11, n = blk & (NN - 1);
    int t = threadIdx.x;
    const float* inr = inner + ((size_t)b * NN + n) * NN;
    float xx = nrm[b * NN + n];
    float dloc[8];
    float vmax = -INFINITY;
#pragma unroll
    for (int i = 0; i < 8; ++i) {
        int m = t + i * 256;
        float pd = (xx - 2.f * inr[m]) + nrm[BNr + b * NN + m];
        float d = pd > 0.f ? sqrtf(pd) : 0.f;
        dloc[i] = d;
        vmax = fmaxf(vmax, -d);
    }
    red[t] = vmax; __syncthreads();
    for (int s = 128; s > 0; s >>= 1) { if (t < s) red[t] = fmaxf(red[t], red[t + s]); __syncthreads(); }
    vmax = red[0]; __syncthreads();
    const float* tp = tgt + (size_t)b * 3 * NN;
    float se = 0.f, s0 = 0.f, s1 = 0.f, s2 = 0.f;
#pragma unroll
    for (int i = 0; i < 8; ++i) {
        int m = t + i * 256;
        float p = expf(-dloc[i] - vmax);
        se += p;
        s0 += p * tp[m]; s1 += p * tp[NN + m]; s2 += p * tp[2 * NN + m];
    }
    red[t] = se; __syncthreads();
    for (int s = 128; s > 0; s >>= 1) { if (t < s) red[t] += red[t + s]; __syncthreads(); }
    float tot = red[0]; __syncthreads();
    red[t] = s0; __syncthreads();
    for (int s = 128; s > 0; s >>= 1) { if (t < s) red[t] += red[t + s]; __syncthreads(); }
    float o0v = red[0]; __syncthreads();
    red[t] = s1; __syncthreads();
    for (int s = 128; s > 0; s >>= 1) { if (t < s) red[t] += red[t + s]; __syncthreads(); }
    float o1v = red[0]; __syncthreads();
    red[t] = s2; __syncthreads();
    for (int s = 128; s > 0; s >>= 1) { if (t < s) red[t] += red[t + s]; __syncthreads(); }
    float o2v = red[0];
    if (t == 0) {
        out[(size_t)b * 3 * NN + n]          = o0v / tot;
        out[(size_t)b * 3 * NN + NN + n]     = o1v / tot;
        out[(size_t)b * 3 * NN + 2 * NN + n] = o2v / tot;
    }
}

// ------------------------------------------------------------- driver -----
extern "C" void kernel_launch(void* const* d_in, const int* in_sizes, int n_in,
                              void* d_out, int out_size, void* d_ws, size_t ws_size,
                              hipStream_t stream) {
    const float* src = (const float*)d_in[0];
    const float* tgt = (const float*)d_in[1];
    const float* w1  = (const float*)d_in[2];
    const float* w2  = (const float*)d_in[3];
    const float* w3  = (const float*)d_in[4];
    const float* w4  = (const float*)d_in[5];
    const float* w5  = (const float*)d_in[6];
    const float* g1  = (const float*)d_in[7];
    const float* g2  = (const float*)d_in[8];
    const float* g3  = (const float*)d_in[9];
    const float* g4  = (const float*)d_in[10];
    const float* g5  = (const float*)d_in[11];
    const float* b1  = (const float*)d_in[12];
    const float* b2  = (const float*)d_in[13];
    const float* b3  = (const float*)d_in[14];
    const float* b4  = (const float*)d_in[15];
    const float* b5  = (const float*)d_in[16];
    float* out = (float*)d_out;
    char* ws = (char*)d_ws;
    (void)in_sizes; (void)n_in;

    size_t off = 0;
    auto alloc = [&](size_t bytes) { size_t o = off; off = (off + bytes + 255) & ~(size_t)255; return o; };
    int*   idx  = (int*)(ws + alloc((size_t)SR * 4));                 // 2 MB
    bf16*  H2   = (bf16*)(ws + alloc((size_t)SR * 64 * 2));           // 64 MB (overlay inner f32)
    bf16*  cat  = (bf16*)(ws + alloc((size_t)GG * BNr * 512 * 2));    // 16 MB
    bf16*  embB = (bf16*)(ws + alloc((size_t)GG * BNr * 512 * 2));    // 16 MB
    float* nrm  = (float*)(ws + alloc((size_t)GG * BNr * 4));
    float* sums = (float*)(ws + alloc(2048 * 4));
    float* prm  = (float*)(ws + alloc(5 * 2048 * 4));
    bf16*  w3b  = (bf16*)(ws + alloc(8192 * 2));
    bf16*  w4b  = (bf16*)(ws + alloc(32768 * 2));
    bf16*  w5b  = (bf16*)(ws + alloc(262144 * 2));
    float* P1 = prm, *P2 = prm + 2048, *P3 = prm + 4096, *P4 = prm + 6144, *P5 = prm + 8192;
    float* inner = (float*)H2;   // overlay: SR*64*2 bytes == B*N*N*4 bytes exactly

    if (ws_size < off) {
        hipMemsetAsync(d_out, 0, (size_t)out_size * 4, stream);
        return;
    }

    knn_kernel<<<GG * BB * NN, 256, 0, stream>>>(src, tgt, idx);
    cvt_kernel<<<32, 256, 0, stream>>>(w3, w3b, 8192);
    cvt_kernel<<<128, 256, 0, stream>>>(w4, w4b, 32768);
    cvt_kernel<<<1024, 256, 0, stream>>>(w5, w5b, 262144);

    // layer 1: stats -> P1
    zero_kernel<<<8, 256, 0, stream>>>(sums, 2048);
    l1stats_kernel<<<SR / 64, 256, 0, stream>>>(src, tgt, w1, idx, sums);
    finalize_bn_kernel<<<1, 128, 0, stream>>>(sums, 64, g1, b1, (float)SGr, P1);

    // layer 2: stats then apply (writes H2 + x1,x2)
    zero_kernel<<<8, 256, 0, stream>>>(sums, 2048);
    l2chain_kernel<0><<<SR / 64, 256, 0, stream>>>(src, tgt, w1, w2, idx, P1, nullptr, nullptr, nullptr, sums);
    finalize_bn_kernel<<<1, 128, 0, stream>>>(sums, 64, g2, b2, (float)SGr, P2);
    l2chain_kernel<1><<<SR / 64, 256, 0, stream>>>(src, tgt, w1, w2, idx, P1, P2, H2, cat, nullptr);

    // layer 3 stats (MFMA GEMM on H2, no store)
    zero_kernel<<<8, 256, 0, stream>>>(sums, 2048);
    mfma_gemm<1, 4><<<dim3(SR / 512, 2, 1), 256, 0, stream>>>(
        H2, w3b, nullptr, nullptr, 64, 0, 0, 0, 0, SGr, nullptr, sums);
    finalize_bn_kernel<<<2, 128, 0, stream>>>(sums, 128, g3, b3, (float)SGr, P3);

    // layers 3+4 chain (MFMA): stats then apply
    zero_kernel<<<8, 256, 0, stream>>>(sums, 2048);
    chain34_mfma<0><<<1024, 512, 138240, stream>>>(H2, w3b, w4b, P3, nullptr, nullptr, sums);
    finalize_bn_kernel<<<4, 128, 0, stream>>>(sums, 256, g4, b4, (float)SGr, P4);
    chain34_mfma<1><<<1024, 512, 138240, stream>>>(H2, w3b, w4b, P3, P4, cat, nullptr);

    // layer 5 (MFMA): stats then apply -> embB (bf16)
    zero_kernel<<<8, 256, 0, stream>>>(sums, 2048);
    mfma_gemm<1, 1><<<dim3(GG * BNr / 128, 8, 1), 256, 0, stream>>>(
        cat, w5b, nullptr, nullptr, 512, 0, 0, 0, 0, BNr, nullptr, sums);
    finalize_bn_kernel<<<8, 128, 0, stream>>>(sums, 512, g5, b5, (float)BNr, P5);
    mfma_gemm<2, 1><<<dim3(GG * BNr / 128, 8, 1), 256, 0, stream>>>(
        cat, w5b, nullptr, embB, 512, 512, 0, 0, 0, BNr, P5, nullptr);

    // embedding norms (from the same bf16 values used for inner products)
    norms_b_kernel<<<GG * BNr, 256, 0, stream>>>(embB, nrm);

    // inner products: per-batch embB_src x embB_tgt^T -> inner (overlay on H2)
    mfma_gemm<0, 1><<<dim3(NN / 128, NN / 64, BB), 256, 0, stream>>>(
        embB, embB + (size_t)BNr * 512, inner, nullptr, 512, 2048,
        (long long)NN * 512, (long long)NN * 512, (long long)NN * NN,
        SGr, nullptr, nullptr);

    // distance + softmax + weighted sum of tgt points
    corr_kernel<<<BB * NN, 256, 0, stream>>>(inner, nrm, tgt, out);
}

// Round 4
// 1408.754 us; speedup vs baseline: 3.6676x; 1.5091x over previous
//
#include <hip/hip_runtime.h>
#include <hip/hip_bf16.h>
#include <math.h>

#define BB 4
#define NN 2048
#define KK 32
#define GG 2
constexpr int BNr = BB * NN;       // 8192 point-rows per group
constexpr int SGr = BB * NN * KK;  // 262144 sample rows per group
constexpr int SR  = GG * SGr;      // 524288 total sample rows

typedef __hip_bfloat16 bf16;
typedef __attribute__((ext_vector_type(8))) short bf16x8;
typedef __attribute__((ext_vector_type(4))) float f32x4;
__device__ __forceinline__ float b2f(bf16 v) { return __bfloat162float(v); }
__device__ __forceinline__ bf16  f2b(float v) { return __float2bfloat16(v); }

// XOR swizzles for LDS tiles (byte-offset based; row = stride 128B / 256B)
#define SWZ128(b) ((b) ^ ((((b) >> 7) & 7) << 4))
#define SWZ256(b) ((b) ^ ((((b) >> 8) & 7) << 4))

// ------------------------------------------------- kNN (wave-per-query) ---
// 4 waves/block = 4 queries of the same cloud. Lane l owns points m=s*64+l
// (32 register slots). Selection: 32x {local argmin, wave argmin via
// shfl_xor, invalidate} -- no __syncthreads in the loop.
__global__ __launch_bounds__(256) void knn_kernel(const float* __restrict__ src,
                                                  const float* __restrict__ tgt,
                                                  int* __restrict__ idx_out) {
    __shared__ float pts[3 * NN];   // 24 KB
    __shared__ float xxs[NN];       // 8 KB
    int blk = blockIdx.x;           // (g*B+b)*(NN/4) + chunk
    int gb = blk >> 9;              // / (NN/4)
    int chunk = blk & 511;
    int g = gb >> 2, b = gb & 3;
    const float* x = (g == 0 ? src : tgt) + (size_t)b * 3 * NN;
    int t = threadIdx.x;
    for (int i = t; i < 3 * NN; i += 256) pts[i] = x[i];
    __syncthreads();
    for (int m = t; m < NN; m += 256) {
        float p0 = pts[m], p1 = pts[NN + m], p2 = pts[2 * NN + m];
        xxs[m] = p0 * p0 + p1 * p1 + p2 * p2;
    }
    __syncthreads();
    int w = t >> 6, l = t & 63;
    int n = chunk * 4 + w;
    float q0 = pts[n], q1 = pts[NN + n], q2 = pts[2 * NN + n];
    float xxn = xxs[n];
    float d2[32];
#pragma unroll
    for (int s = 0; s < 32; ++s) {
        int m = s * 64 + l;
        float dot = q0 * pts[m] + q1 * pts[NN + m] + q2 * pts[2 * NN + m];
        d2[s] = (xxn - 2.0f * dot) + xxs[m];
    }
    int* outp = idx_out + ((size_t)gb * NN + n) * KK;
    for (int k = 0; k < KK; ++k) {
        // local argmin over 32 static slots (tie -> smaller s == smaller m)
        float bv = d2[0]; int bs = 0;
#pragma unroll
        for (int s = 1; s < 32; ++s)
            if (d2[s] < bv) { bv = d2[s]; bs = s; }
        int bm = bs * 64 + l;
        // wave argmin on (value, m), tie -> smaller m
#pragma unroll
        for (int off = 1; off < 64; off <<= 1) {
            float ov = __shfl_xor(bv, off);
            int om = __shfl_xor(bm, off);
            if (ov < bv || (ov == bv && om < bm)) { bv = ov; bm = om; }
        }
        if (l == (bm & 63)) {
            int s = bm >> 6;
#pragma unroll
            for (int ss = 0; ss < 32; ++ss)
                if (ss == s) d2[ss] = INFINITY;
        }
        if (l == 0) outp[k] = bm;
    }
}

// ---------------------------------------------------------------- misc ----
__global__ void zero_kernel(float* __restrict__ p, int n) {
    int i = blockIdx.x * 256 + threadIdx.x;
    if (i < n) p[i] = 0.f;
}

__global__ void cvt_kernel(const float* __restrict__ a, bf16* __restrict__ o, int n) {
    int i = blockIdx.x * 256 + threadIdx.x;
    if (i < n) o[i] = f2b(a[i]);
}

__global__ void finalize_bn_kernel(const float* __restrict__ sums, int C,
                                   const float* __restrict__ gamma,
                                   const float* __restrict__ beta,
                                   float cnt, float* __restrict__ params) {
    int i = blockIdx.x * blockDim.x + threadIdx.x;
    if (i >= GG * C) return;
    int g = i / C, c = i - g * C;
    float s  = sums[(g * 512 + c) * 2 + 0];
    float sq = sums[(g * 512 + c) * 2 + 1];
    float mean = s / cnt;
    float var = sq / cnt - mean * mean;
    if (var < 0.f) var = 0.f;
    float sc = gamma[c] * rsqrtf(var + 1e-5f);
    params[(g * 512 + c) * 2 + 0] = sc;
    params[(g * 512 + c) * 2 + 1] = beta[c] - mean * sc;
}

// ----------------------------------------------------------- l1 stats -----
__global__ __launch_bounds__(256) void l1stats_kernel(const float* __restrict__ src,
                                                      const float* __restrict__ tgt,
                                                      const float* __restrict__ w1,
                                                      const int* __restrict__ idx,
                                                      float* __restrict__ sums) {
    __shared__ float feat[64][8];
    __shared__ float w1s[64][8];
    __shared__ float epi[16][128];
    int t = threadIdx.x;
    int row0 = blockIdx.x * 64;
    int g = row0 / SGr;
    for (int i = t; i < 384; i += 256) w1s[i / 6][i % 6] = w1[i];
    if (t < 64) {
        int rr = row0 + t;
        int nrow = rr >> 5;
        int n = nrow & (NN - 1);
        int gb = nrow >> 11;
        int b = gb & 3, gg = gb >> 2;
        const float* x = (gg ? tgt : src) + (size_t)b * 3 * NN;
        int j = idx[rr];
        feat[t][0] = x[j]; feat[t][1] = x[NN + j]; feat[t][2] = x[2 * NN + j];
        feat[t][3] = x[n]; feat[t][4] = x[NN + n]; feat[t][5] = x[2 * NN + n];
    }
    __syncthreads();
    int ty = t >> 4, tx = t & 15;
    float acc[4][4] = {};
#pragma unroll
    for (int c = 0; c < 6; ++c) {
        float av[4], bv[4];
#pragma unroll
        for (int i = 0; i < 4; ++i) av[i] = feat[ty * 4 + i][c];
#pragma unroll
        for (int j = 0; j < 4; ++j) bv[j] = w1s[tx * 4 + j][c];
#pragma unroll
        for (int i = 0; i < 4; ++i)
#pragma unroll
            for (int j = 0; j < 4; ++j) acc[i][j] = fmaf(av[i], bv[j], acc[i][j]);
    }
#pragma unroll
    for (int j = 0; j < 4; ++j) {
        float s = acc[0][j] + acc[1][j] + acc[2][j] + acc[3][j];
        float q = acc[0][j] * acc[0][j] + acc[1][j] * acc[1][j] +
                  acc[2][j] * acc[2][j] + acc[3][j] * acc[3][j];
        epi[ty][tx * 4 + j] = s;
        epi[ty][64 + tx * 4 + j] = q;
    }
    __syncthreads();
    if (t < 64) {
        float s = 0.f, q = 0.f;
        for (int r = 0; r < 16; ++r) { s += epi[r][t]; q += epi[r][64 + t]; }
        atomicAdd(&sums[(g * 512 + t) * 2 + 0], s);
        atomicAdd(&sums[(g * 512 + t) * 2 + 1], q);
    }
}

// ----------------------------------------------- layers 1+2 chain ---------
template <int APPLY>
__global__ __launch_bounds__(256) void l2chain_kernel(
    const float* __restrict__ src, const float* __restrict__ tgt,
    const float* __restrict__ w1, const float* __restrict__ w2,
    const int* __restrict__ idx, const float* __restrict__ p1,
    const float* __restrict__ p2, bf16* __restrict__ H2,
    bf16* __restrict__ cat, float* __restrict__ sums) {
    __shared__ float feat[64][8];
    __shared__ float w1s[64][8];
    __shared__ float F1[64][68];
    __shared__ float w2s[64][68];
    __shared__ float epi[16][128];
    int t = threadIdx.x;
    int row0 = blockIdx.x * 64;
    int g = row0 / SGr;
    for (int i = t; i < 384; i += 256) w1s[i / 6][i % 6] = w1[i];
    for (int i = t; i < 4096; i += 256) w2s[i >> 6][i & 63] = w2[i];
    if (t < 64) {
        int rr = row0 + t;
        int nrow = rr >> 5;
        int n = nrow & (NN - 1);
        int gb = nrow >> 11;
        int b = gb & 3, gg = gb >> 2;
        const float* x = (gg ? tgt : src) + (size_t)b * 3 * NN;
        int j = idx[rr];
        feat[t][0] = x[j]; feat[t][1] = x[NN + j]; feat[t][2] = x[2 * NN + j];
        feat[t][3] = x[n]; feat[t][4] = x[NN + n]; feat[t][5] = x[2 * NN + n];
    }
    __syncthreads();
    int ty = t >> 4, tx = t & 15;
    float acc[4][4] = {};
#pragma unroll
    for (int c = 0; c < 6; ++c) {
        float av[4], bv[4];
#pragma unroll
        for (int i = 0; i < 4; ++i) av[i] = feat[ty * 4 + i][c];
#pragma unroll
        for (int j = 0; j < 4; ++j) bv[j] = w1s[tx * 4 + j][c];
#pragma unroll
        for (int i = 0; i < 4; ++i)
#pragma unroll
            for (int j = 0; j < 4; ++j) acc[i][j] = fmaf(av[i], bv[j], acc[i][j]);
    }
#pragma unroll
    for (int j = 0; j < 4; ++j) {
        int o = tx * 4 + j;
        float sc = p1[(g * 512 + o) * 2], sh = p1[(g * 512 + o) * 2 + 1];
#pragma unroll
        for (int i = 0; i < 4; ++i) {
            float v = fmaf(acc[i][j], sc, sh);
            v = v > 0.f ? v : 0.f;
            acc[i][j] = v;
            F1[ty * 4 + i][tx * 4 + j] = v;
        }
    }
    __syncthreads();
    if (APPLY) {
#pragma unroll
        for (int j = 0; j < 4; ++j) {
            float m = fmaxf(fmaxf(acc[0][j], acc[1][j]), fmaxf(acc[2][j], acc[3][j]));
            epi[ty][tx * 4 + j] = m;
        }
        __syncthreads();
        if (t < 128) {
            int pt = t >> 6, o = t & 63;
            float m = 0.f;
            for (int r = pt * 8; r < pt * 8 + 8; ++r) m = fmaxf(m, epi[r][o]);
            cat[((size_t)(row0 >> 5) + pt) * 512 + o] = f2b(m);
        }
        __syncthreads();
    }
    float a2[4][4] = {};
#pragma unroll 8
    for (int kk = 0; kk < 64; ++kk) {
        float av[4], bv[4];
#pragma unroll
        for (int i = 0; i < 4; ++i) av[i] = F1[ty * 4 + i][kk];
#pragma unroll
        for (int j = 0; j < 4; ++j) bv[j] = w2s[tx * 4 + j][kk];
#pragma unroll
        for (int i = 0; i < 4; ++i)
#pragma unroll
            for (int j = 0; j < 4; ++j) a2[i][j] = fmaf(av[i], bv[j], a2[i][j]);
    }
    if (!APPLY) {
#pragma unroll
        for (int j = 0; j < 4; ++j) {
            float s = a2[0][j] + a2[1][j] + a2[2][j] + a2[3][j];
            float q = a2[0][j] * a2[0][j] + a2[1][j] * a2[1][j] +
                      a2[2][j] * a2[2][j] + a2[3][j] * a2[3][j];
            epi[ty][tx * 4 + j] = s;
            epi[ty][64 + tx * 4 + j] = q;
        }
        __syncthreads();
        if (t < 64) {
            float s = 0.f, q = 0.f;
            for (int r = 0; r < 16; ++r) { s += epi[r][t]; q += epi[r][64 + t]; }
            atomicAdd(&sums[(g * 512 + t) * 2 + 0], s);
            atomicAdd(&sums[(g * 512 + t) * 2 + 1], q);
        }
    } else {
#pragma unroll
        for (int j = 0; j < 4; ++j) {
            int o = tx * 4 + j;
            float sc = p2[(g * 512 + o) * 2], sh = p2[(g * 512 + o) * 2 + 1];
            float m = 0.f;
#pragma unroll
            for (int i = 0; i < 4; ++i) {
                float v = fmaf(a2[i][j], sc, sh);
                v = v > 0.f ? v : 0.f;
                H2[(size_t)(row0 + ty * 4 + i) * 64 + o] = f2b(v);
                m = fmaxf(m, v);
            }
            epi[ty][o] = m;
        }
        __syncthreads();
        if (t < 128) {
            int pt = t >> 6, o = t & 63;
            float m = 0.f;
            for (int r = pt * 8; r < pt * 8 + 8; ++r) m = fmaxf(m, epi[r][o]);
            cat[((size_t)(row0 >> 5) + pt) * 512 + 64 + o] = f2b(m);
        }
    }
}

// ------------------------------------------- MFMA chain: layers 3+4 -------
template <int APPLY>
__global__ __launch_bounds__(512, 2) void chain34_mfma(
    const bf16* __restrict__ H2, const bf16* __restrict__ w3b,
    const bf16* __restrict__ w4b, const float* __restrict__ p3,
    const float* __restrict__ p4, bf16* __restrict__ cat,
    float* __restrict__ sums) {
    extern __shared__ char smem[];
    char* W3s = smem;                      // 16384  [128][64] bf16 swz128
    char* W4s = smem + 16384;              // 65536  [256][128] bf16 swz256
    char* A2s = smem + 81920;              // 16384  [128][64] bf16 swz128
    char* F3s = smem + 98304;              // 32768  [128][128] bf16 swz256
    float* P3s = (float*)(smem + 131072);  // 256 f32
    float* P4s = (float*)(smem + 132096);  // 512 f32
    float* epi = (float*)(smem + 134144);  // 4096 B

    int tid = threadIdx.x;
    int w = tid >> 6, l = tid & 63, lg = l >> 4, lr = l & 15;
    long long rowB0 = (long long)blockIdx.x * 512;
    int g = (int)(rowB0 / SGr);

    for (int s = tid; s < 1024; s += 512)
        *(bf16x8*)(W3s + SWZ128(s * 16)) = *(const bf16x8*)(w3b + s * 8);
    for (int s = tid; s < 4096; s += 512)
        *(bf16x8*)(W4s + SWZ256(s * 16)) = *(const bf16x8*)(w4b + s * 8);
    if (tid < 256) P3s[tid] = p3[g * 1024 + tid];
    P4s[tid] = p4 ? p4[g * 1024 + tid] : 0.f;
    if (!APPLY) epi[tid] = 0.f;

    for (int chunk = 0; chunk < 4; ++chunk) {
        long long row0 = rowB0 + chunk * 128;
        for (int s = tid; s < 1024; s += 512)
            *(bf16x8*)(A2s + SWZ128(s * 16)) = *(const bf16x8*)(H2 + row0 * 64 + s * 8);
        if (APPLY) { ((int*)epi)[tid] = 0; ((int*)epi)[tid + 512] = 0; }
        __syncthreads();

        f32x4 acc3[8] = {};
#pragma unroll
        for (int ks = 0; ks < 2; ++ks) {
            bf16x8 a = *(bf16x8*)(A2s + SWZ128(((16 * w + lr) * 64 + ks * 32 + lg * 8) * 2));
#pragma unroll
            for (int j = 0; j < 8; ++j) {
                bf16x8 b = *(bf16x8*)(W3s + SWZ128(((16 * j + lr) * 64 + ks * 32 + lg * 8) * 2));
                acc3[j] = __builtin_amdgcn_mfma_f32_16x16x32_bf16(a, b, acc3[j], 0, 0, 0);
            }
        }
#pragma unroll
        for (int j = 0; j < 8; ++j) {
            int c = 16 * j + lr;
            float sc = P3s[c * 2], sh = P3s[c * 2 + 1];
#pragma unroll
            for (int r = 0; r < 4; ++r) {
                float v = fmaf(acc3[j][r], sc, sh);
                v = v > 0.f ? v : 0.f;
                int rowi = 16 * w + 4 * lg + r;
                *(bf16*)(F3s + SWZ256((rowi * 128 + c) * 2)) = f2b(v);
            }
        }
        __syncthreads();

        f32x4 acc4[16] = {};
#pragma unroll
        for (int ks = 0; ks < 4; ++ks) {
            bf16x8 a = *(bf16x8*)(F3s + SWZ256(((16 * w + lr) * 128 + ks * 32 + lg * 8) * 2));
#pragma unroll
            for (int j = 0; j < 16; ++j) {
                bf16x8 b = *(bf16x8*)(W4s + SWZ256(((16 * j + lr) * 128 + ks * 32 + lg * 8) * 2));
                acc4[j] = __builtin_amdgcn_mfma_f32_16x16x32_bf16(a, b, acc4[j], 0, 0, 0);
            }
        }

        if (!APPLY) {
#pragma unroll
            for (int j = 0; j < 16; ++j) {
                int c = 16 * j + lr;
                float s = acc4[j][0] + acc4[j][1] + acc4[j][2] + acc4[j][3];
                float q = acc4[j][0] * acc4[j][0] + acc4[j][1] * acc4[j][1] +
                          acc4[j][2] * acc4[j][2] + acc4[j][3] * acc4[j][3];
                s += __shfl_xor(s, 16); s += __shfl_xor(s, 32);
                q += __shfl_xor(q, 16); q += __shfl_xor(q, 32);
                if (lg == 0) {
                    atomicAdd(&epi[c * 2], s);
                    atomicAdd(&epi[c * 2 + 1], q);
                }
            }
        } else {
#pragma unroll
            for (int j = 0; j < 16; ++j) {
                int c = 16 * j + lr;
                float sc = P4s[c * 2], sh = P4s[c * 2 + 1];
                float m = 0.f;
#pragma unroll
                for (int r = 0; r < 4; ++r) {
                    float v = fmaf(acc4[j][r], sc, sh);
                    v = v > 0.f ? v : 0.f;
                    m = fmaxf(m, v);
                }
                m = fmaxf(m, __shfl_xor(m, 16));
                m = fmaxf(m, __shfl_xor(m, 32));
                if (lg == 0)
                    atomicMax((int*)epi + (w >> 1) * 256 + c, __float_as_int(m));
            }
            __syncthreads();
            long long pt0 = row0 >> 5;
            for (int e = tid; e < 1024; e += 512) {
                int p = e >> 8, c = e & 255;
                cat[(pt0 + p) * 512 + 256 + c] = f2b(__int_as_float(((int*)epi)[p * 256 + c]));
            }
            {
                int p = tid >> 7, c = tid & 127;
                float m = 0.f;
                for (int r = 0; r < 32; ++r)
                    m = fmaxf(m, b2f(*(bf16*)(F3s + SWZ256(((p * 32 + r) * 128 + c) * 2))));
                cat[(pt0 + p) * 512 + 128 + c] = f2b(m);
            }
            __syncthreads();
        }
    }
    if (!APPLY) {
        __syncthreads();
        atomicAdd(&sums[g * 1024 + tid], epi[tid]);
    }
}

// ----------------------------------------------------- generic MFMA GEMM --
template <int MODE, int CH>
__global__ __launch_bounds__(256, 4) void mfma_gemm(
    const bf16* __restrict__ A, const bf16* __restrict__ Wt,
    float* __restrict__ OutF, bf16* __restrict__ OutB,
    int Cin, int ldOut, long long sA, long long sW, long long sO,
    int rowsPerGroup, const float* __restrict__ params, float* __restrict__ sums) {
    __shared__ char As[16384];   // [128][64] bf16 swz128
    __shared__ char Bs[8192];    // [64][64] bf16 swz128
    __shared__ float epi[128];
    int tid = threadIdx.x;
    int w = tid >> 6, l = tid & 63, lg = l >> 4, lr = l & 15;
    int bz = blockIdx.z;
    const bf16* Ap = A + (long long)bz * sA;
    const bf16* Wp = Wt + (long long)bz * sW;
    int o0 = blockIdx.y * 64;
    long long rowB0 = (long long)blockIdx.x * (128 * CH);
    int g = (int)(rowB0 / rowsPerGroup);
    if (MODE == 1 && tid < 128) epi[tid] = 0.f;
    int wr = (w >> 1) * 64, wc = (w & 1) * 32;

    for (int ch = 0; ch < CH; ++ch) {
        long long row0 = rowB0 + (long long)ch * 128;
        f32x4 acc[4][2] = {};
        for (int k0 = 0; k0 < Cin; k0 += 64) {
            __syncthreads();
            for (int s = tid; s < 1024; s += 256)
                *(bf16x8*)(As + SWZ128(s * 16)) =
                    *(const bf16x8*)(Ap + (row0 + (s >> 3)) * Cin + k0 + (s & 7) * 8);
            for (int s = tid; s < 512; s += 256)
                *(bf16x8*)(Bs + SWZ128(s * 16)) =
                    *(const bf16x8*)(Wp + (long long)(o0 + (s >> 3)) * Cin + k0 + (s & 7) * 8);
            __syncthreads();
#pragma unroll
            for (int ks = 0; ks < 2; ++ks) {
                bf16x8 b0 = *(bf16x8*)(Bs + SWZ128(((wc + lr) * 64 + ks * 32 + lg * 8) * 2));
                bf16x8 b1 = *(bf16x8*)(Bs + SWZ128(((wc + 16 + lr) * 64 + ks * 32 + lg * 8) * 2));
#pragma unroll
                for (int i = 0; i < 4; ++i) {
                    bf16x8 a = *(bf16x8*)(As + SWZ128(((wr + 16 * i + lr) * 64 + ks * 32 + lg * 8) * 2));
                    acc[i][0] = __builtin_amdgcn_mfma_f32_16x16x32_bf16(a, b0, acc[i][0], 0, 0, 0);
                    acc[i][1] = __builtin_amdgcn_mfma_f32_16x16x32_bf16(a, b1, acc[i][1], 0, 0, 0);
                }
            }
        }
        if (MODE == 1) {
#pragma unroll
            for (int j = 0; j < 2; ++j) {
                int c = wc + 16 * j + lr;
                float s = 0.f, q = 0.f;
#pragma unroll
                for (int i = 0; i < 4; ++i)
#pragma unroll
                    for (int r = 0; r < 4; ++r) {
                        float v = acc[i][j][r];
                        s += v; q += v * v;
                    }
                s += __shfl_xor(s, 16); s += __shfl_xor(s, 32);
                q += __shfl_xor(q, 16); q += __shfl_xor(q, 32);
                if (lg == 0) {
                    atomicAdd(&epi[c * 2], s);
                    atomicAdd(&epi[c * 2 + 1], q);
                }
            }
        } else if (MODE == 2) {
#pragma unroll
            for (int j = 0; j < 2; ++j) {
                int gc = o0 + wc + 16 * j + lr;
                float sc = params[(g * 512 + gc) * 2], sh = params[(g * 512 + gc) * 2 + 1];
#pragma unroll
                for (int i = 0; i < 4; ++i)
#pragma unroll
                    for (int r = 0; r < 4; ++r) {
                        long long gr = row0 + wr + 16 * i + 4 * lg + r;
                        float v = fmaf(acc[i][j][r], sc, sh);
                        v = v > 0.f ? v : 0.f;
                        OutB[gr * ldOut + gc] = f2b(v);
                    }
            }
        } else {
            float* Op = OutF + (long long)bz * sO;
#pragma unroll
            for (int j = 0; j < 2; ++j) {
                int gc = o0 + wc + 16 * j + lr;
#pragma unroll
                for (int i = 0; i < 4; ++i)
#pragma unroll
                    for (int r = 0; r < 4; ++r) {
                        long long gr = row0 + wr + 16 * i + 4 * lg + r;
                        Op[gr * ldOut + gc] = acc[i][j][r];
                    }
            }
        }
    }
    if (MODE == 1) {
        __syncthreads();
        if (tid < 128) atomicAdd(&sums[g * 1024 + o0 * 2 + tid], epi[tid]);
    }
}

// ------------------------------------------------------------ norms -------
__global__ __launch_bounds__(256) void norms_b_kernel(const bf16* __restrict__ emb,
                                                      float* __restrict__ nrm) {
    __shared__ float red[256];
    int row = blockIdx.x; int t = threadIdx.x;
    float s = 0.f;
    for (int c = t; c < 512; c += 256) { float v = b2f(emb[(size_t)row * 512 + c]); s += v * v; }
    red[t] = s; __syncthreads();
    for (int st = 128; st > 0; st >>= 1) { if (t < st) red[t] += red[t + st]; __syncthreads(); }
    if (t == 0) nrm[row] = red[0];
}

// -------------------------------- distance + softmax + weighted sum -------
__global__ __launch_bounds__(256) void corr_kernel(const float* __restrict__ inner,
                                                   const float* __restrict__ nrm,
                                                   const float* __restrict__ tgt,
                                                   float* __restrict__ out) {
    __shared__ float red[256];
    int blk = blockIdx.x;                 // b*N + n
    int b = blk >> 11, n = blk & (NN - 1);
    int t = threadIdx.x;
    const float* inr = inner + ((size_t)b * NN + n) * NN;
    float xx = nrm[b * NN + n];
    float dloc[8];
    float vmax = -INFINITY;
#pragma unroll
    for (int i = 0; i < 8; ++i) {
        int m = t + i * 256;
        float pd = (xx - 2.f * inr[m]) + nrm[BNr + b * NN + m];
        float d = pd > 0.f ? sqrtf(pd) : 0.f;
        dloc[i] = d;
        vmax = fmaxf(vmax, -d);
    }
    red[t] = vmax; __syncthreads();
    for (int s = 128; s > 0; s >>= 1) { if (t < s) red[t] = fmaxf(red[t], red[t + s]); __syncthreads(); }
    vmax = red[0]; __syncthreads();
    const float* tp = tgt + (size_t)b * 3 * NN;
    float se = 0.f, s0 = 0.f, s1 = 0.f, s2 = 0.f;
#pragma unroll
    for (int i = 0; i < 8; ++i) {
        int m = t + i * 256;
        float p = expf(-dloc[i] - vmax);
        se += p;
        s0 += p * tp[m]; s1 += p * tp[NN + m]; s2 += p * tp[2 * NN + m];
    }
    red[t] = se; __syncthreads();
    for (int s = 128; s > 0; s >>= 1) { if (t < s) red[t] += red[t + s]; __syncthreads(); }
    float tot = red[0]; __syncthreads();
    red[t] = s0; __syncthreads();
    for (int s = 128; s > 0; s >>= 1) { if (t < s) red[t] += red[t + s]; __syncthreads(); }
    float o0v = red[0]; __syncthreads();
    red[t] = s1; __syncthreads();
    for (int s = 128; s > 0; s >>= 1) { if (t < s) red[t] += red[t + s]; __syncthreads(); }
    float o1v = red[0]; __syncthreads();
    red[t] = s2; __syncthreads();
    for (int s = 128; s > 0; s >>= 1) { if (t < s) red[t] += red[t + s]; __syncthreads(); }
    float o2v = red[0];
    if (t == 0) {
        out[(size_t)b * 3 * NN + n]          = o0v / tot;
        out[(size_t)b * 3 * NN + NN + n]     = o1v / tot;
        out[(size_t)b * 3 * NN + 2 * NN + n] = o2v / tot;
    }
}

// ------------------------------------------------------------- driver -----
extern "C" void kernel_launch(void* const* d_in, const int* in_sizes, int n_in,
                              void* d_out, int out_size, void* d_ws, size_t ws_size,
                              hipStream_t stream) {
    const float* src = (const float*)d_in[0];
    const float* tgt = (const float*)d_in[1];
    const float* w1  = (const float*)d_in[2];
    const float* w2  = (const float*)d_in[3];
    const float* w3  = (const float*)d_in[4];
    const float* w4  = (const float*)d_in[5];
    const float* w5  = (const float*)d_in[6];
    const float* g1  = (const float*)d_in[7];
    const float* g2  = (const float*)d_in[8];
    const float* g3  = (const float*)d_in[9];
    const float* g4  = (const float*)d_in[10];
    const float* g5  = (const float*)d_in[11];
    const float* b1  = (const float*)d_in[12];
    const float* b2  = (const float*)d_in[13];
    const float* b3  = (const float*)d_in[14];
    const float* b4  = (const float*)d_in[15];
    const float* b5  = (const float*)d_in[16];
    float* out = (float*)d_out;
    char* ws = (char*)d_ws;
    (void)in_sizes; (void)n_in;

    size_t off = 0;
    auto alloc = [&](size_t bytes) { size_t o = off; off = (off + bytes + 255) & ~(size_t)255; return o; };
    int*   idx  = (int*)(ws + alloc((size_t)SR * 4));                 // 2 MB
    bf16*  H2   = (bf16*)(ws + alloc((size_t)SR * 64 * 2));           // 64 MB (overlay inner f32)
    bf16*  cat  = (bf16*)(ws + alloc((size_t)GG * BNr * 512 * 2));    // 16 MB
    bf16*  embB = (bf16*)(ws + alloc((size_t)GG * BNr * 512 * 2));    // 16 MB
    float* nrm  = (float*)(ws + alloc((size_t)GG * BNr * 4));
    float* sums = (float*)(ws + alloc(2048 * 4));
    float* prm  = (float*)(ws + alloc(5 * 2048 * 4));
    bf16*  w3b  = (bf16*)(ws + alloc(8192 * 2));
    bf16*  w4b  = (bf16*)(ws + alloc(32768 * 2));
    bf16*  w5b  = (bf16*)(ws + alloc(262144 * 2));
    float* P1 = prm, *P2 = prm + 2048, *P3 = prm + 4096, *P4 = prm + 6144, *P5 = prm + 8192;
    float* inner = (float*)H2;   // overlay: SR*64*2 bytes == B*N*N*4 bytes exactly

    if (ws_size < off) {
        hipMemsetAsync(d_out, 0, (size_t)out_size * 4, stream);
        return;
    }

    knn_kernel<<<GG * BB * NN / 4, 256, 0, stream>>>(src, tgt, idx);
    cvt_kernel<<<32, 256, 0, stream>>>(w3, w3b, 8192);
    cvt_kernel<<<128, 256, 0, stream>>>(w4, w4b, 32768);
    cvt_kernel<<<1024, 256, 0, stream>>>(w5, w5b, 262144);

    // layer 1: stats -> P1
    zero_kernel<<<8, 256, 0, stream>>>(sums, 2048);
    l1stats_kernel<<<SR / 64, 256, 0, stream>>>(src, tgt, w1, idx, sums);
    finalize_bn_kernel<<<1, 128, 0, stream>>>(sums, 64, g1, b1, (float)SGr, P1);

    // layer 2: stats then apply (writes H2 + x1,x2)
    zero_kernel<<<8, 256, 0, stream>>>(sums, 2048);
    l2chain_kernel<0><<<SR / 64, 256, 0, stream>>>(src, tgt, w1, w2, idx, P1, nullptr, nullptr, nullptr, sums);
    finalize_bn_kernel<<<1, 128, 0, stream>>>(sums, 64, g2, b2, (float)SGr, P2);
    l2chain_kernel<1><<<SR / 64, 256, 0, stream>>>(src, tgt, w1, w2, idx, P1, P2, H2, cat, nullptr);

    // layer 3 stats (MFMA GEMM on H2, no store)
    zero_kernel<<<8, 256, 0, stream>>>(sums, 2048);
    mfma_gemm<1, 4><<<dim3(SR / 512, 2, 1), 256, 0, stream>>>(
        H2, w3b, nullptr, nullptr, 64, 0, 0, 0, 0, SGr, nullptr, sums);
    finalize_bn_kernel<<<2, 128, 0, stream>>>(sums, 128, g3, b3, (float)SGr, P3);

    // layers 3+4 chain (MFMA): stats then apply
    zero_kernel<<<8, 256, 0, stream>>>(sums, 2048);
    chain34_mfma<0><<<1024, 512, 138240, stream>>>(H2, w3b, w4b, P3, nullptr, nullptr, sums);
    finalize_bn_kernel<<<4, 128, 0, stream>>>(sums, 256, g4, b4, (float)SGr, P4);
    chain34_mfma<1><<<1024, 512, 138240, stream>>>(H2, w3b, w4b, P3, P4, cat, nullptr);

    // layer 5 (MFMA): stats then apply -> embB (bf16)
    zero_kernel<<<8, 256, 0, stream>>>(sums, 2048);
    mfma_gemm<1, 1><<<dim3(GG * BNr / 128, 8, 1), 256, 0, stream>>>(
        cat, w5b, nullptr, nullptr, 512, 0, 0, 0, 0, BNr, nullptr, sums);
    finalize_bn_kernel<<<8, 128, 0, stream>>>(sums, 512, g5, b5, (float)BNr, P5);
    mfma_gemm<2, 1><<<dim3(GG * BNr / 128, 8, 1), 256, 0, stream>>>(
        cat, w5b, nullptr, embB, 512, 512, 0, 0, 0, BNr, P5, nullptr);

    // embedding norms (from the same bf16 values used for inner products)
    norms_b_kernel<<<GG * BNr, 256, 0, stream>>>(embB, nrm);

    // inner products: per-batch embB_src x embB_tgt^T -> inner (overlay on H2)
    mfma_gemm<0, 1><<<dim3(NN / 128, NN / 64, BB), 256, 0, stream>>>(
        embB, embB + (size_t)BNr * 512, inner, nullptr, 512, 2048,
        (long long)NN * 512, (long long)NN * 512, (long long)NN * NN,
        SGr, nullptr, nullptr);

    // distance + softmax + weighted sum of tgt points
    corr_kernel<<<BB * NN, 256, 0, stream>>>(inner, nrm, tgt, out);
}

// Round 5
// 827.757 us; speedup vs baseline: 6.2419x; 1.7019x over previous
//
#include <hip/hip_runtime.h>
#include <hip/hip_bf16.h>
#include <math.h>

#define BB 4
#define NN 2048
#define KK 32
#define GG 2
constexpr int BNr = BB * NN;       // 8192 point-rows per group
constexpr int SGr = BB * NN * KK;  // 262144 sample rows per group
constexpr int SR  = GG * SGr;      // 524288 total sample rows

typedef __hip_bfloat16 bf16;
typedef __attribute__((ext_vector_type(8))) short bf16x8;
typedef __attribute__((ext_vector_type(4))) float f32x4;
__device__ __forceinline__ float b2f(bf16 v) { return __bfloat162float(v); }
__device__ __forceinline__ bf16  f2b(float v) { return __float2bfloat16(v); }
__device__ __forceinline__ short f2bs(float v) { bf16 b = f2b(v); return *(short*)&b; }

// XOR swizzles for LDS tiles (byte-offset based; row = stride 128B / 256B)
#define SWZ128(b) ((b) ^ ((((b) >> 7) & 7) << 4))
#define SWZ256(b) ((b) ^ ((((b) >> 8) & 7) << 4))

// ------------------------------------------------- kNN (wave-per-query) ---
__global__ __launch_bounds__(256) void knn_kernel(const float* __restrict__ src,
                                                  const float* __restrict__ tgt,
                                                  int* __restrict__ idx_out) {
    __shared__ float pts[3 * NN];   // 24 KB
    __shared__ float xxs[NN];       // 8 KB
    int blk = blockIdx.x;           // (g*B+b)*(NN/4) + chunk
    int gb = blk >> 9;              // / (NN/4)
    int chunk = blk & 511;
    int g = gb >> 2, b = gb & 3;
    const float* x = (g == 0 ? src : tgt) + (size_t)b * 3 * NN;
    int t = threadIdx.x;
    for (int i = t; i < 3 * NN; i += 256) pts[i] = x[i];
    __syncthreads();
    for (int m = t; m < NN; m += 256) {
        float p0 = pts[m], p1 = pts[NN + m], p2 = pts[2 * NN + m];
        xxs[m] = p0 * p0 + p1 * p1 + p2 * p2;
    }
    __syncthreads();
    int w = t >> 6, l = t & 63;
    int n = chunk * 4 + w;
    float q0 = pts[n], q1 = pts[NN + n], q2 = pts[2 * NN + n];
    float xxn = xxs[n];
    float d2[32];
#pragma unroll
    for (int s = 0; s < 32; ++s) {
        int m = s * 64 + l;
        float dot = q0 * pts[m] + q1 * pts[NN + m] + q2 * pts[2 * NN + m];
        d2[s] = (xxn - 2.0f * dot) + xxs[m];
    }
    int* outp = idx_out + ((size_t)gb * NN + n) * KK;
    for (int k = 0; k < KK; ++k) {
        float bv = d2[0]; int bs = 0;
#pragma unroll
        for (int s = 1; s < 32; ++s)
            if (d2[s] < bv) { bv = d2[s]; bs = s; }
        int bm = bs * 64 + l;
#pragma unroll
        for (int off = 1; off < 64; off <<= 1) {
            float ov = __shfl_xor(bv, off);
            int om = __shfl_xor(bm, off);
            if (ov < bv || (ov == bv && om < bm)) { bv = ov; bm = om; }
        }
        if (l == (bm & 63)) {
            int s = bm >> 6;
#pragma unroll
            for (int ss = 0; ss < 32; ++ss)
                if (ss == s) d2[ss] = INFINITY;
        }
        if (l == 0) outp[k] = bm;
    }
}

// ---------------------------------------------------------------- misc ----
__global__ void zero_kernel(float* __restrict__ p, int n) {
    int i = blockIdx.x * 256 + threadIdx.x;
    if (i < n) p[i] = 0.f;
}

__global__ void cvt_kernel(const float* __restrict__ a, bf16* __restrict__ o, int n) {
    int i = blockIdx.x * 256 + threadIdx.x;
    if (i < n) o[i] = f2b(a[i]);
}

__global__ void finalize_bn_kernel(const float* __restrict__ sums, int C,
                                   const float* __restrict__ gamma,
                                   const float* __restrict__ beta,
                                   float cnt, float* __restrict__ params) {
    int i = blockIdx.x * blockDim.x + threadIdx.x;
    if (i >= GG * C) return;
    int g = i / C, c = i - g * C;
    float s  = sums[(g * 512 + c) * 2 + 0];
    float sq = sums[(g * 512 + c) * 2 + 1];
    float mean = s / cnt;
    float var = sq / cnt - mean * mean;
    if (var < 0.f) var = 0.f;
    float sc = gamma[c] * rsqrtf(var + 1e-5f);
    params[(g * 512 + c) * 2 + 0] = sc;
    params[(g * 512 + c) * 2 + 1] = beta[c] - mean * sc;
}

// ----------------------------------------------- MFMA layers 1+2 ----------
// 256 thr / 4 waves, 256 rows per block. Gather feeds MFMA A-frags directly
// (K=32 zero-padded: only lg==0 lanes carry the 6 features).
// MODE 0: h1pre stats. MODE 1: h2pre stats. MODE 2: apply -> H2 + x1,x2.
template <int MODE>
__global__ __launch_bounds__(256, 3) void l12_mfma(
    const float* __restrict__ src, const float* __restrict__ tgt,
    const float* __restrict__ w1, const bf16* __restrict__ w2b,
    const int* __restrict__ idx, const float* __restrict__ p1,
    const float* __restrict__ p2, bf16* __restrict__ H2,
    bf16* __restrict__ cat, float* __restrict__ sums) {
    __shared__ char F1s[32768];    // [256][64] bf16 swz128
    __shared__ char W2s[8192];     // [64][64] bf16 swz128
    __shared__ float epiA[512];    // stats: [64][2] sums / apply: x1 int-max [8][64]
    __shared__ float epiB[512];    // apply: x2 int-max [8][64]
    int tid = threadIdx.x;
    int w = tid >> 6, l = tid & 63, lg = l >> 4, lr = l & 15;
    long long row0 = (long long)blockIdx.x * 256;
    int g = (int)(row0 / SGr);

    // zero epi
    epiA[tid] = 0.f; epiA[tid + 256] = 0.f;
    if (MODE == 2) { epiB[tid] = 0.f; epiB[tid + 256] = 0.f; }
    // stage W2
    if (MODE >= 1) {
        for (int s = tid; s < 512; s += 256)
            *(bf16x8*)(W2s + SWZ128(s * 16)) = *(const bf16x8*)(w2b + s * 8);
    }

    // gather A-frags (4 row tiles of 16) and w1 B-frags
    bf16x8 af[4];
#pragma unroll
    for (int i = 0; i < 4; ++i) {
        af[i] = (bf16x8){0, 0, 0, 0, 0, 0, 0, 0};
        if (lg == 0) {
            int rr = (int)row0 + w * 64 + 16 * i + lr;
            int nrow = rr >> 5;
            int n = nrow & (NN - 1);
            int gb = nrow >> 11;
            int b = gb & 3, gg = gb >> 2;
            const float* x = (gg ? tgt : src) + (size_t)b * 3 * NN;
            int j = idx[rr];
            af[i][0] = f2bs(x[j]);
            af[i][1] = f2bs(x[NN + j]);
            af[i][2] = f2bs(x[2 * NN + j]);
            af[i][3] = f2bs(x[n]);
            af[i][4] = f2bs(x[NN + n]);
            af[i][5] = f2bs(x[2 * NN + n]);
        }
    }
    bf16x8 bf1[4];
#pragma unroll
    for (int j = 0; j < 4; ++j) {
        bf1[j] = (bf16x8){0, 0, 0, 0, 0, 0, 0, 0};
        if (lg == 0) {
            int o = 16 * j + lr;
#pragma unroll
            for (int c = 0; c < 6; ++c) bf1[j][c] = f2bs(w1[o * 6 + c]);
        }
    }

    // layer 1 MFMA: 256x6(pad32) @ w1^T -> 256x64
    f32x4 acc1[4][4] = {};
#pragma unroll
    for (int i = 0; i < 4; ++i)
#pragma unroll
        for (int j = 0; j < 4; ++j)
            acc1[i][j] = __builtin_amdgcn_mfma_f32_16x16x32_bf16(af[i], bf1[j], acc1[i][j], 0, 0, 0);

    __syncthreads();   // epi zeroed + W2s staged

    if (MODE == 0) {
        // h1pre stats
#pragma unroll
        for (int j = 0; j < 4; ++j) {
            int c = 16 * j + lr;
            float s = 0.f, q = 0.f;
#pragma unroll
            for (int i = 0; i < 4; ++i)
#pragma unroll
                for (int r = 0; r < 4; ++r) { float v = acc1[i][j][r]; s += v; q += v * v; }
            s += __shfl_xor(s, 16); s += __shfl_xor(s, 32);
            q += __shfl_xor(q, 16); q += __shfl_xor(q, 32);
            if (lg == 0) {
                atomicAdd(&epiA[c * 2], s);
                atomicAdd(&epiA[c * 2 + 1], q);
            }
        }
        __syncthreads();
        if (tid < 128) atomicAdd(&sums[g * 1024 + tid], epiA[tid]);
        return;
    }

    // bn1 + relu -> F1 (bf16), x1 max (MODE 2)
#pragma unroll
    for (int j = 0; j < 4; ++j) {
        int c = 16 * j + lr;
        float sc = p1[(g * 512 + c) * 2], sh = p1[(g * 512 + c) * 2 + 1];
#pragma unroll
        for (int i = 0; i < 4; ++i) {
            float m = 0.f;
#pragma unroll
            for (int r = 0; r < 4; ++r) {
                float v = fmaf(acc1[i][j][r], sc, sh);
                v = v > 0.f ? v : 0.f;
                m = fmaxf(m, v);
                int rowi = w * 64 + 16 * i + 4 * lg + r;
                *(bf16*)(F1s + SWZ128((rowi * 64 + c) * 2)) = f2b(v);
            }
            if (MODE == 2) {
                int p = 2 * w + (i >> 1);
                atomicMax((int*)epiA + p * 64 + c, __float_as_int(m));
            }
        }
    }
    __syncthreads();   // F1 + x1 complete

    if (MODE == 2) {
        long long pt0 = row0 >> 5;
        for (int e = tid; e < 512; e += 256) {
            int p = e >> 6, c = e & 63;
            cat[(pt0 + p) * 512 + c] = f2b(__int_as_float(((int*)epiA)[p * 64 + c]));
        }
    }

    // layer 2 MFMA: F1 @ w2^T -> 256x64
    f32x4 acc2[4][4] = {};
#pragma unroll
    for (int ks = 0; ks < 2; ++ks) {
        bf16x8 bv[4];
#pragma unroll
        for (int j = 0; j < 4; ++j)
            bv[j] = *(bf16x8*)(W2s + SWZ128(((16 * j + lr) * 64 + ks * 32 + lg * 8) * 2));
#pragma unroll
        for (int i = 0; i < 4; ++i) {
            bf16x8 a = *(bf16x8*)(F1s + SWZ128(((w * 64 + 16 * i + lr) * 64 + ks * 32 + lg * 8) * 2));
#pragma unroll
            for (int j = 0; j < 4; ++j)
                acc2[i][j] = __builtin_amdgcn_mfma_f32_16x16x32_bf16(a, bv[j], acc2[i][j], 0, 0, 0);
        }
    }

    if (MODE == 1) {
        // h2pre stats
#pragma unroll
        for (int j = 0; j < 4; ++j) {
            int c = 16 * j + lr;
            float s = 0.f, q = 0.f;
#pragma unroll
            for (int i = 0; i < 4; ++i)
#pragma unroll
                for (int r = 0; r < 4; ++r) { float v = acc2[i][j][r]; s += v; q += v * v; }
            s += __shfl_xor(s, 16); s += __shfl_xor(s, 32);
            q += __shfl_xor(q, 16); q += __shfl_xor(q, 32);
            if (lg == 0) {
                atomicAdd(&epiA[c * 2], s);
                atomicAdd(&epiA[c * 2 + 1], q);
            }
        }
        __syncthreads();
        if (tid < 128) atomicAdd(&sums[g * 1024 + tid], epiA[tid]);
        return;
    }

    // MODE 2: bn2 + relu -> H2, x2 max -> cat
#pragma unroll
    for (int j = 0; j < 4; ++j) {
        int c = 16 * j + lr;
        float sc = p2[(g * 512 + c) * 2], sh = p2[(g * 512 + c) * 2 + 1];
#pragma unroll
        for (int i = 0; i < 4; ++i) {
            float m = 0.f;
#pragma unroll
            for (int r = 0; r < 4; ++r) {
                float v = fmaf(acc2[i][j][r], sc, sh);
                v = v > 0.f ? v : 0.f;
                m = fmaxf(m, v);
                long long gr = row0 + w * 64 + 16 * i + 4 * lg + r;
                H2[gr * 64 + c] = f2b(v);
            }
            int p = 2 * w + (i >> 1);
            atomicMax((int*)epiB + p * 64 + c, __float_as_int(m));
        }
    }
    __syncthreads();
    {
        long long pt0 = row0 >> 5;
        for (int e = tid; e < 512; e += 256) {
            int p = e >> 6, c = e & 63;
            cat[(pt0 + p) * 512 + 64 + c] = f2b(__int_as_float(((int*)epiB)[p * 64 + c]));
        }
    }
}

// ------------------------------------------- MFMA chain: layers 3+4 -------
template <int APPLY>
__global__ __launch_bounds__(512, 2) void chain34_mfma(
    const bf16* __restrict__ H2, const bf16* __restrict__ w3b,
    const bf16* __restrict__ w4b, const float* __restrict__ p3,
    const float* __restrict__ p4, bf16* __restrict__ cat,
    float* __restrict__ sums) {
    extern __shared__ char smem[];
    char* W3s = smem;                      // 16384  [128][64] bf16 swz128
    char* W4s = smem + 16384;              // 65536  [256][128] bf16 swz256
    char* A2s = smem + 81920;              // 16384  [128][64] bf16 swz128
    char* F3s = smem + 98304;              // 32768  [128][128] bf16 swz256
    float* P3s = (float*)(smem + 131072);  // 256 f32
    float* P4s = (float*)(smem + 132096);  // 512 f32
    float* epi = (float*)(smem + 134144);  // 4096 B

    int tid = threadIdx.x;
    int w = tid >> 6, l = tid & 63, lg = l >> 4, lr = l & 15;
    long long rowB0 = (long long)blockIdx.x * 512;
    int g = (int)(rowB0 / SGr);

    for (int s = tid; s < 1024; s += 512)
        *(bf16x8*)(W3s + SWZ128(s * 16)) = *(const bf16x8*)(w3b + s * 8);
    for (int s = tid; s < 4096; s += 512)
        *(bf16x8*)(W4s + SWZ256(s * 16)) = *(const bf16x8*)(w4b + s * 8);
    if (tid < 256) P3s[tid] = p3[g * 1024 + tid];
    P4s[tid] = p4 ? p4[g * 1024 + tid] : 0.f;
    if (!APPLY) epi[tid] = 0.f;

    for (int chunk = 0; chunk < 4; ++chunk) {
        long long row0 = rowB0 + chunk * 128;
        for (int s = tid; s < 1024; s += 512)
            *(bf16x8*)(A2s + SWZ128(s * 16)) = *(const bf16x8*)(H2 + row0 * 64 + s * 8);
        if (APPLY) { ((int*)epi)[tid] = 0; ((int*)epi)[tid + 512] = 0; }
        __syncthreads();

        f32x4 acc3[8] = {};
#pragma unroll
        for (int ks = 0; ks < 2; ++ks) {
            bf16x8 a = *(bf16x8*)(A2s + SWZ128(((16 * w + lr) * 64 + ks * 32 + lg * 8) * 2));
#pragma unroll
            for (int j = 0; j < 8; ++j) {
                bf16x8 b = *(bf16x8*)(W3s + SWZ128(((16 * j + lr) * 64 + ks * 32 + lg * 8) * 2));
                acc3[j] = __builtin_amdgcn_mfma_f32_16x16x32_bf16(a, b, acc3[j], 0, 0, 0);
            }
        }
#pragma unroll
        for (int j = 0; j < 8; ++j) {
            int c = 16 * j + lr;
            float sc = P3s[c * 2], sh = P3s[c * 2 + 1];
#pragma unroll
            for (int r = 0; r < 4; ++r) {
                float v = fmaf(acc3[j][r], sc, sh);
                v = v > 0.f ? v : 0.f;
                int rowi = 16 * w + 4 * lg + r;
                *(bf16*)(F3s + SWZ256((rowi * 128 + c) * 2)) = f2b(v);
            }
        }
        __syncthreads();

        f32x4 acc4[16] = {};
#pragma unroll
        for (int ks = 0; ks < 4; ++ks) {
            bf16x8 a = *(bf16x8*)(F3s + SWZ256(((16 * w + lr) * 128 + ks * 32 + lg * 8) * 2));
#pragma unroll
            for (int j = 0; j < 16; ++j) {
                bf16x8 b = *(bf16x8*)(W4s + SWZ256(((16 * j + lr) * 128 + ks * 32 + lg * 8) * 2));
                acc4[j] = __builtin_amdgcn_mfma_f32_16x16x32_bf16(a, b, acc4[j], 0, 0, 0);
            }
        }

        if (!APPLY) {
#pragma unroll
            for (int j = 0; j < 16; ++j) {
                int c = 16 * j + lr;
                float s = acc4[j][0] + acc4[j][1] + acc4[j][2] + acc4[j][3];
                float q = acc4[j][0] * acc4[j][0] + acc4[j][1] * acc4[j][1] +
                          acc4[j][2] * acc4[j][2] + acc4[j][3] * acc4[j][3];
                s += __shfl_xor(s, 16); s += __shfl_xor(s, 32);
                q += __shfl_xor(q, 16); q += __shfl_xor(q, 32);
                if (lg == 0) {
                    atomicAdd(&epi[c * 2], s);
                    atomicAdd(&epi[c * 2 + 1], q);
                }
            }
        } else {
#pragma unroll
            for (int j = 0; j < 16; ++j) {
                int c = 16 * j + lr;
                float sc = P4s[c * 2], sh = P4s[c * 2 + 1];
                float m = 0.f;
#pragma unroll
                for (int r = 0; r < 4; ++r) {
                    float v = fmaf(acc4[j][r], sc, sh);
                    v = v > 0.f ? v : 0.f;
                    m = fmaxf(m, v);
                }
                m = fmaxf(m, __shfl_xor(m, 16));
                m = fmaxf(m, __shfl_xor(m, 32));
                if (lg == 0)
                    atomicMax((int*)epi + (w >> 1) * 256 + c, __float_as_int(m));
            }
            __syncthreads();
            long long pt0 = row0 >> 5;
            for (int e = tid; e < 1024; e += 512) {
                int p = e >> 8, c = e & 255;
                cat[(pt0 + p) * 512 + 256 + c] = f2b(__int_as_float(((int*)epi)[p * 256 + c]));
            }
            {
                int p = tid >> 7, c = tid & 127;
                float m = 0.f;
                for (int r = 0; r < 32; ++r)
                    m = fmaxf(m, b2f(*(bf16*)(F3s + SWZ256(((p * 32 + r) * 128 + c) * 2))));
                cat[(pt0 + p) * 512 + 128 + c] = f2b(m);
            }
            __syncthreads();
        }
    }
    if (!APPLY) {
        __syncthreads();
        atomicAdd(&sums[g * 1024 + tid], epi[tid]);
    }
}

// ----------------------------------------------------- generic MFMA GEMM --
template <int MODE, int CH>
__global__ __launch_bounds__(256, 4) void mfma_gemm(
    const bf16* __restrict__ A, const bf16* __restrict__ Wt,
    float* __restrict__ OutF, bf16* __restrict__ OutB,
    int Cin, int ldOut, long long sA, long long sW, long long sO,
    int rowsPerGroup, const float* __restrict__ params, float* __restrict__ sums) {
    __shared__ char As[16384];   // [128][64] bf16 swz128
    __shared__ char Bs[8192];    // [64][64] bf16 swz128
    __shared__ float epi[128];
    int tid = threadIdx.x;
    int w = tid >> 6, l = tid & 63, lg = l >> 4, lr = l & 15;
    int bz = blockIdx.z;
    const bf16* Ap = A + (long long)bz * sA;
    const bf16* Wp = Wt + (long long)bz * sW;
    int o0 = blockIdx.y * 64;
    long long rowB0 = (long long)blockIdx.x * (128 * CH);
    int g = (int)(rowB0 / rowsPerGroup);
    if (MODE == 1 && tid < 128) epi[tid] = 0.f;
    int wr = (w >> 1) * 64, wc = (w & 1) * 32;

    for (int ch = 0; ch < CH; ++ch) {
        long long row0 = rowB0 + (long long)ch * 128;
        f32x4 acc[4][2] = {};
        for (int k0 = 0; k0 < Cin; k0 += 64) {
            __syncthreads();
            for (int s = tid; s < 1024; s += 256)
                *(bf16x8*)(As + SWZ128(s * 16)) =
                    *(const bf16x8*)(Ap + (row0 + (s >> 3)) * Cin + k0 + (s & 7) * 8);
            for (int s = tid; s < 512; s += 256)
                *(bf16x8*)(Bs + SWZ128(s * 16)) =
                    *(const bf16x8*)(Wp + (long long)(o0 + (s >> 3)) * Cin + k0 + (s & 7) * 8);
            __syncthreads();
#pragma unroll
            for (int ks = 0; ks < 2; ++ks) {
                bf16x8 b0 = *(bf16x8*)(Bs + SWZ128(((wc + lr) * 64 + ks * 32 + lg * 8) * 2));
                bf16x8 b1 = *(bf16x8*)(Bs + SWZ128(((wc + 16 + lr) * 64 + ks * 32 + lg * 8) * 2));
#pragma unroll
                for (int i = 0; i < 4; ++i) {
                    bf16x8 a = *(bf16x8*)(As + SWZ128(((wr + 16 * i + lr) * 64 + ks * 32 + lg * 8) * 2));
                    acc[i][0] = __builtin_amdgcn_mfma_f32_16x16x32_bf16(a, b0, acc[i][0], 0, 0, 0);
                    acc[i][1] = __builtin_amdgcn_mfma_f32_16x16x32_bf16(a, b1, acc[i][1], 0, 0, 0);
                }
            }
        }
        if (MODE == 1) {
#pragma unroll
            for (int j = 0; j < 2; ++j) {
                int c = wc + 16 * j + lr;
                float s = 0.f, q = 0.f;
#pragma unroll
                for (int i = 0; i < 4; ++i)
#pragma unroll
                    for (int r = 0; r < 4; ++r) {
                        float v = acc[i][j][r];
                        s += v; q += v * v;
                    }
                s += __shfl_xor(s, 16); s += __shfl_xor(s, 32);
                q += __shfl_xor(q, 16); q += __shfl_xor(q, 32);
                if (lg == 0) {
                    atomicAdd(&epi[c * 2], s);
                    atomicAdd(&epi[c * 2 + 1], q);
                }
            }
        } else if (MODE == 2) {
#pragma unroll
            for (int j = 0; j < 2; ++j) {
                int gc = o0 + wc + 16 * j + lr;
                float sc = params[(g * 512 + gc) * 2], sh = params[(g * 512 + gc) * 2 + 1];
#pragma unroll
                for (int i = 0; i < 4; ++i)
#pragma unroll
                    for (int r = 0; r < 4; ++r) {
                        long long gr = row0 + wr + 16 * i + 4 * lg + r;
                        float v = fmaf(acc[i][j][r], sc, sh);
                        v = v > 0.f ? v : 0.f;
                        OutB[gr * ldOut + gc] = f2b(v);
                    }
            }
        } else {
            float* Op = OutF + (long long)bz * sO;
#pragma unroll
            for (int j = 0; j < 2; ++j) {
                int gc = o0 + wc + 16 * j + lr;
#pragma unroll
                for (int i = 0; i < 4; ++i)
#pragma unroll
                    for (int r = 0; r < 4; ++r) {
                        long long gr = row0 + wr + 16 * i + 4 * lg + r;
                        Op[gr * ldOut + gc] = acc[i][j][r];
                    }
            }
        }
    }
    if (MODE == 1) {
        __syncthreads();
        if (tid < 128) atomicAdd(&sums[g * 1024 + o0 * 2 + tid], epi[tid]);
    }
}

// ------------------------------------------------------------ norms -------
__global__ __launch_bounds__(256) void norms_b_kernel(const bf16* __restrict__ emb,
                                                      float* __restrict__ nrm) {
    __shared__ float red[256];
    int row = blockIdx.x; int t = threadIdx.x;
    float s = 0.f;
    for (int c = t; c < 512; c += 256) { float v = b2f(emb[(size_t)row * 512 + c]); s += v * v; }
    red[t] = s; __syncthreads();
    for (int st = 128; st > 0; st >>= 1) { if (t < st) red[t] += red[t + st]; __syncthreads(); }
    if (t == 0) nrm[row] = red[0];
}

// -------------------------------- distance + softmax + weighted sum -------
__global__ __launch_bounds__(256) void corr_kernel(const float* __restrict__ inner,
                                                   const float* __restrict__ nrm,
                                                   const float* __restrict__ tgt,
                                                   float* __restrict__ out) {
    __shared__ float red[256];
    int blk = blockIdx.x;                 // b*N + n
    int b = blk >> 11, n = blk & (NN - 1);
    int t = threadIdx.x;
    const float* inr = inner + ((size_t)b * NN + n) * NN;
    float xx = nrm[b * NN + n];
    float dloc[8];
    float vmax = -INFINITY;
#pragma unroll
    for (int i = 0; i < 8; ++i) {
        int m = t + i * 256;
        float pd = (xx - 2.f * inr[m]) + nrm[BNr + b * NN + m];
        float d = pd > 0.f ? sqrtf(pd) : 0.f;
        dloc[i] = d;
        vmax = fmaxf(vmax, -d);
    }
    red[t] = vmax; __syncthreads();
    for (int s = 128; s > 0; s >>= 1) { if (t < s) red[t] = fmaxf(red[t], red[t + s]); __syncthreads(); }
    vmax = red[0]; __syncthreads();
    const float* tp = tgt + (size_t)b * 3 * NN;
    float se = 0.f, s0 = 0.f, s1 = 0.f, s2 = 0.f;
#pragma unroll
    for (int i = 0; i < 8; ++i) {
        int m = t + i * 256;
        float p = expf(-dloc[i] - vmax);
        se += p;
        s0 += p * tp[m]; s1 += p * tp[NN + m]; s2 += p * tp[2 * NN + m];
    }
    red[t] = se; __syncthreads();
    for (int s = 128; s > 0; s >>= 1) { if (t < s) red[t] += red[t + s]; __syncthreads(); }
    float tot = red[0]; __syncthreads();
    red[t] = s0; __syncthreads();
    for (int s = 128; s > 0; s >>= 1) { if (t < s) red[t] += red[t + s]; __syncthreads(); }
    float o0v = red[0]; __syncthreads();
    red[t] = s1; __syncthreads();
    for (int s = 128; s > 0; s >>= 1) { if (t < s) red[t] += red[t + s]; __syncthreads(); }
    float o1v = red[0]; __syncthreads();
    red[t] = s2; __syncthreads();
    for (int s = 128; s > 0; s >>= 1) { if (t < s) red[t] += red[t + s]; __syncthreads(); }
    float o2v = red[0];
    if (t == 0) {
        out[(size_t)b * 3 * NN + n]          = o0v / tot;
        out[(size_t)b * 3 * NN + NN + n]     = o1v / tot;
        out[(size_t)b * 3 * NN + 2 * NN + n] = o2v / tot;
    }
}

// ------------------------------------------------------------- driver -----
extern "C" void kernel_launch(void* const* d_in, const int* in_sizes, int n_in,
                              void* d_out, int out_size, void* d_ws, size_t ws_size,
                              hipStream_t stream) {
    const float* src = (const float*)d_in[0];
    const float* tgt = (const float*)d_in[1];
    const float* w1  = (const float*)d_in[2];
    const float* w2  = (const float*)d_in[3];
    const float* w3  = (const float*)d_in[4];
    const float* w4  = (const float*)d_in[5];
    const float* w5  = (const float*)d_in[6];
    const float* g1  = (const float*)d_in[7];
    const float* g2  = (const float*)d_in[8];
    const float* g3  = (const float*)d_in[9];
    const float* g4  = (const float*)d_in[10];
    const float* g5  = (const float*)d_in[11];
    const float* b1  = (const float*)d_in[12];
    const float* b2  = (const float*)d_in[13];
    const float* b3  = (const float*)d_in[14];
    const float* b4  = (const float*)d_in[15];
    const float* b5  = (const float*)d_in[16];
    float* out = (float*)d_out;
    char* ws = (char*)d_ws;
    (void)in_sizes; (void)n_in;

    size_t off = 0;
    auto alloc = [&](size_t bytes) { size_t o = off; off = (off + bytes + 255) & ~(size_t)255; return o; };
    int*   idx  = (int*)(ws + alloc((size_t)SR * 4));                 // 2 MB
    bf16*  H2   = (bf16*)(ws + alloc((size_t)SR * 64 * 2));           // 64 MB (overlay inner f32)
    bf16*  cat  = (bf16*)(ws + alloc((size_t)GG * BNr * 512 * 2));    // 16 MB
    bf16*  embB = (bf16*)(ws + alloc((size_t)GG * BNr * 512 * 2));    // 16 MB
    float* nrm  = (float*)(ws + alloc((size_t)GG * BNr * 4));
    float* sums = (float*)(ws + alloc(2048 * 4));
    float* prm  = (float*)(ws + alloc(5 * 2048 * 4));
    bf16*  w2b  = (bf16*)(ws + alloc(4096 * 2));
    bf16*  w3b  = (bf16*)(ws + alloc(8192 * 2));
    bf16*  w4b  = (bf16*)(ws + alloc(32768 * 2));
    bf16*  w5b  = (bf16*)(ws + alloc(262144 * 2));
    float* P1 = prm, *P2 = prm + 2048, *P3 = prm + 4096, *P4 = prm + 6144, *P5 = prm + 8192;
    float* inner = (float*)H2;   // overlay: SR*64*2 bytes == B*N*N*4 bytes exactly

    if (ws_size < off) {
        hipMemsetAsync(d_out, 0, (size_t)out_size * 4, stream);
        return;
    }

    knn_kernel<<<GG * BB * NN / 4, 256, 0, stream>>>(src, tgt, idx);
    cvt_kernel<<<16, 256, 0, stream>>>(w2, w2b, 4096);
    cvt_kernel<<<32, 256, 0, stream>>>(w3, w3b, 8192);
    cvt_kernel<<<128, 256, 0, stream>>>(w4, w4b, 32768);
    cvt_kernel<<<1024, 256, 0, stream>>>(w5, w5b, 262144);

    // layer 1 stats -> P1
    zero_kernel<<<8, 256, 0, stream>>>(sums, 2048);
    l12_mfma<0><<<SR / 256, 256, 0, stream>>>(src, tgt, w1, w2b, idx, nullptr, nullptr, nullptr, nullptr, sums);
    finalize_bn_kernel<<<1, 128, 0, stream>>>(sums, 64, g1, b1, (float)SGr, P1);

    // layer 2 stats -> P2, then apply (writes H2 + x1,x2)
    zero_kernel<<<8, 256, 0, stream>>>(sums, 2048);
    l12_mfma<1><<<SR / 256, 256, 0, stream>>>(src, tgt, w1, w2b, idx, P1, nullptr, nullptr, nullptr, sums);
    finalize_bn_kernel<<<1, 128, 0, stream>>>(sums, 64, g2, b2, (float)SGr, P2);
    l12_mfma<2><<<SR / 256, 256, 0, stream>>>(src, tgt, w1, w2b, idx, P1, P2, H2, cat, nullptr);

    // layer 3 stats (MFMA GEMM on H2, no store)
    zero_kernel<<<8, 256, 0, stream>>>(sums, 2048);
    mfma_gemm<1, 4><<<dim3(SR / 512, 2, 1), 256, 0, stream>>>(
        H2, w3b, nullptr, nullptr, 64, 0, 0, 0, 0, SGr, nullptr, sums);
    finalize_bn_kernel<<<2, 128, 0, stream>>>(sums, 128, g3, b3, (float)SGr, P3);

    // layers 3+4 chain (MFMA): stats then apply
    zero_kernel<<<8, 256, 0, stream>>>(sums, 2048);
    chain34_mfma<0><<<1024, 512, 138240, stream>>>(H2, w3b, w4b, P3, nullptr, nullptr, sums);
    finalize_bn_kernel<<<4, 128, 0, stream>>>(sums, 256, g4, b4, (float)SGr, P4);
    chain34_mfma<1><<<1024, 512, 138240, stream>>>(H2, w3b, w4b, P3, P4, cat, nullptr);

    // layer 5 (MFMA): stats then apply -> embB (bf16)
    zero_kernel<<<8, 256, 0, stream>>>(sums, 2048);
    mfma_gemm<1, 1><<<dim3(GG * BNr / 128, 8, 1), 256, 0, stream>>>(
        cat, w5b, nullptr, nullptr, 512, 0, 0, 0, 0, BNr, nullptr, sums);
    finalize_bn_kernel<<<8, 128, 0, stream>>>(sums, 512, g5, b5, (float)BNr, P5);
    mfma_gemm<2, 1><<<dim3(GG * BNr / 128, 8, 1), 256, 0, stream>>>(
        cat, w5b, nullptr, embB, 512, 512, 0, 0, 0, BNr, P5, nullptr);

    // embedding norms (from the same bf16 values used for inner products)
    norms_b_kernel<<<GG * BNr, 256, 0, stream>>>(embB, nrm);

    // inner products: per-batch embB_src x embB_tgt^T -> inner (overlay on H2)
    mfma_gemm<0, 1><<<dim3(NN / 128, NN / 64, BB), 256, 0, stream>>>(
        embB, embB + (size_t)BNr * 512, inner, nullptr, 512, 2048,
        (long long)NN * 512, (long long)NN * 512, (long long)NN * NN,
        SGr, nullptr, nullptr);

    // distance + softmax + weighted sum of tgt points
    corr_kernel<<<BB * NN, 256, 0, stream>>>(inner, nrm, tgt, out);
}